// Round 3
// baseline (478.135 us; speedup 1.0000x reference)
//
#include <hip/hip_runtime.h>
#include <hip/hip_bf16.h>
#include <stdint.h>

#define DIMS 1024
#define STATE 2048
#define BATCH 4
#define SEQ 2048
#define TOKENS 8192   // BATCH*SEQ
#define N1 8192       // STATE + 3*STATE columns of fused GEMM1
#define NCHUNK 16
#define CHUNKL (SEQ / NCHUNK)   // 128

typedef __hip_bfloat16 bf16;
typedef __attribute__((ext_vector_type(8))) short bf16x8;
typedef __attribute__((ext_vector_type(4))) float f32x4;

__device__ __forceinline__ float sigmoidf_(float x) {
  return 1.0f / (1.0f + __expf(-x));
}

// async global->LDS, 16B per lane. LDS dest must be wave-uniform base; HW does base + lane*16.
__device__ __forceinline__ void async_copy16(const void* g, void* l) {
  __builtin_amdgcn_global_load_lds(
      (const __attribute__((address_space(1))) void*)(uintptr_t)g,
      (__attribute__((address_space(3))) void*)(uint32_t)(uintptr_t)l,
      16, 0, 0);
}

// ---------------- weight transpose + fp32->bf16 cast: W[K][N] -> Wt[N][K] ----------------
__global__ __launch_bounds__(256) void transpose_bf16_kernel(
    const float* __restrict__ W, bf16* __restrict__ Wt, int K, int N) {
  __shared__ float tile[32][33];
  int tx = threadIdx.x & 31;
  int ty = threadIdx.x >> 5;  // 0..7
  long col = (long)blockIdx.x * 32 + tx;
  long rowb = (long)blockIdx.y * 32;
#pragma unroll
  for (int i = 0; i < 32; i += 8)
    tile[ty + i][tx] = W[(rowb + ty + i) * N + col];
  __syncthreads();
  long ocol = rowb + tx;                      // k index
  long orow = (long)blockIdx.x * 32 + ty;     // n index
#pragma unroll
  for (int i = 0; i < 32; i += 8)
    Wt[(orow + i) * K + ocol] = __float2bfloat16(tile[tx][ty + i]);
}

// ---------------- split RMSNorm -> bf16 ----------------
__global__ __launch_bounds__(256) void rmsnorm_kernel(
    const float* __restrict__ x, const float* __restrict__ ls,
    const float* __restrict__ rs, const float* __restrict__ ss,
    bf16* __restrict__ xn) {
  int token = blockIdx.x;
  int tid = threadIdx.x;  // 256 threads, 4 floats each
  const float4* xt = (const float4*)(x + (long)token * DIMS);
  float4 v = xt[tid];
  float s = v.x * v.x + v.y * v.y + v.z * v.z + v.w * v.w;
#pragma unroll
  for (int d = 32; d > 0; d >>= 1) s += __shfl_down(s, d);
  __shared__ float parts[4];
  if ((tid & 63) == 0) parts[tid >> 6] = s;
  __syncthreads();
  int j = tid * 4;
  bool left = j < 512;  // waves 0,1 cover elements 0..511
  float sum = left ? (parts[0] + parts[1]) : (parts[2] + parts[3]);
  float n = sqrtf(sum * (1.0f / 512.0f));  // ||v||*d^-1/2
  float inv = 1.0f / (n + 1e-8f);
  const float4* sc = (const float4*)(left ? ls : rs);
  float4 g = sc[left ? tid : tid - 128];
  float4 p = ((const float4*)ss)[tid];
  bf16* o = xn + (long)token * DIMS + j;
  o[0] = __float2bfloat16(v.x * g.x * inv * p.x);
  o[1] = __float2bfloat16(v.y * g.y * inv * p.y);
  o[2] = __float2bfloat16(v.z * g.z * inv * p.z);
  o[3] = __float2bfloat16(v.w * g.w * inv * p.w);
}

// ---------------- m97-style GEMM: C[M,N] = A[M,K] @ Bt[N,K]^T ----------------
// LDS uses an XOR k-chunk swizzle (kc = c ^ ((row>>2)&3)) to break the 8-way
// ds_read_b128 bank aliasing of the plain layout down to 2-way (free, m136).
// MFMA operands are SWAPPED (mfma(b,a,acc)): both operands use the identical
// fragment layout, so the product is the same values with output slots
// n-slot(lane&15)=A-row(token), m-slot(q*4+reg)=B-row(channel). Each lane then
// holds 4 CONSECUTIVE channels per acc -> packed 8B/16B stores.
// EPI==0: store bf16 C (4 bf16 = 8B per store).  EPI==1: fp32 C + residual (float4).
template <int EPI>
__global__ __launch_bounds__(256) void gemm_bt(
    const bf16* __restrict__ A, const bf16* __restrict__ Bt,
    void* __restrict__ Cout, const float* __restrict__ resid,
    int M, int N, int K) {
  __shared__ __align__(16) bf16 As[128 * 32];
  __shared__ __align__(16) bf16 Bs[128 * 32];
  int tid = threadIdx.x;
  int lane = tid & 63, wave = tid >> 6;
  int wm = wave & 1, wn = wave >> 1;  // 2x2 wave grid, 64x64 each
  long arow0 = (long)blockIdx.y * 128;
  long brow0 = (long)blockIdx.x * 128;
  int r = lane & 15, q = lane >> 4;
  int sw = q ^ ((r >> 2) & 3);  // swizzled k-chunk for fragment reads
  f32x4 acc[4][4] = {};

  for (int k0 = 0; k0 < K; k0 += 32) {
    __syncthreads();  // previous iter's LDS reads done before overwrite
#pragma unroll
    for (int i = 0; i < 2; i++) {
      int c = (wave * 2 + i) * 64 + lane;  // LDS 16B chunk id, 0..511
      int row = c >> 2;
      int kc = (c & 3) ^ ((row >> 2) & 3);  // source k-chunk (swizzle)
      async_copy16(A + (arow0 + row) * K + k0 + kc * 8, (char*)As + (wave * 2 + i) * 1024);
      async_copy16(Bt + (brow0 + row) * K + k0 + kc * 8, (char*)Bs + (wave * 2 + i) * 1024);
    }
    __syncthreads();  // compiler drains vmcnt(0) before barrier -> LDS visible
    const bf16x8* AsV = (const bf16x8*)As;
    const bf16x8* BsV = (const bf16x8*)Bs;
    bf16x8 af[4], bfr[4];
#pragma unroll
    for (int mt = 0; mt < 4; mt++) af[mt] = AsV[(wm * 64 + mt * 16 + r) * 4 + sw];
#pragma unroll
    for (int nt = 0; nt < 4; nt++) bfr[nt] = BsV[(wn * 64 + nt * 16 + r) * 4 + sw];
#pragma unroll
    for (int mt = 0; mt < 4; mt++)
#pragma unroll
      for (int nt = 0; nt < 4; nt++)
        acc[mt][nt] = __builtin_amdgcn_mfma_f32_16x16x32_bf16(bfr[nt], af[mt], acc[mt][nt], 0, 0, 0);
  }

  // Swapped C/D mapping: token = lane&15 (within mt tile), channel = q*4+reg
  // (within nt tile) -> 4 consecutive channels per lane per acc.
  if (EPI == 0) {
    bf16* C = (bf16*)Cout;
#pragma unroll
    for (int mt = 0; mt < 4; mt++) {
      long row = arow0 + wm * 64 + mt * 16 + r;  // token
#pragma unroll
      for (int nt = 0; nt < 4; nt++) {
        long col = brow0 + wn * 64 + nt * 16 + q * 4;  // channel base
        bf16 tmp[4];
#pragma unroll
        for (int reg = 0; reg < 4; reg++) tmp[reg] = __float2bfloat16(acc[mt][nt][reg]);
        *(uint2*)(C + row * N + col) = *(uint2*)tmp;
      }
    }
  } else {
    float* C = (float*)Cout;
#pragma unroll
    for (int mt = 0; mt < 4; mt++) {
      long row = arow0 + wm * 64 + mt * 16 + r;  // token
#pragma unroll
      for (int nt = 0; nt < 4; nt++) {
        long col = brow0 + wn * 64 + nt * 16 + q * 4;  // channel base
        float4 rv = *(const float4*)(resid + row * N + col);
        float4 ov;
        ov.x = acc[mt][nt][0] + rv.x;
        ov.y = acc[mt][nt][1] + rv.y;
        ov.z = acc[mt][nt][2] + rv.z;
        ov.w = acc[mt][nt][3] + rv.w;
        *(float4*)(C + row * N + col) = ov;
      }
    }
  }
}

// ---------------- chunked gated linear scan ----------------
// Recurrence: h_t = a_t*h_{t-1} + u_t, a_t = sigmoid(Kraw_{t-1}) (a_0=1),
// u_t = uraw_t*sigmoid(gin_t)*(1-sigmoid(Kraw_t)).  Over a chunk this composes
// to h_out = A*h_in + U, enabling a 3-pass parallel scan over NCHUNK chunks.

// Pass A: per (batch, channel, chunk) thread reduces the chunk to (A, U).
__global__ __launch_bounds__(256) void chunk_summary_kernel(
    const bf16* __restrict__ C1, float* __restrict__ carryA,
    float* __restrict__ carryU) {
  int b = blockIdx.x;
  int ch = blockIdx.y * 256 + threadIdx.x;
  int chunk = blockIdx.z;
  int t0 = chunk * CHUNKL;
  long base = ((long)b * SEQ) * N1 + ch;
  float kp = 0.0f;
  if (chunk != 0) kp = __bfloat162float(C1[base + (long)(t0 - 1) * N1]);
  float a_first = (chunk == 0) ? 1.0f : sigmoidf_(kp);
  float A = 1.0f, U = 0.0f;
#pragma unroll 8
  for (int t = t0; t < t0 + CHUNKL; t++) {
    long off = base + (long)t * N1;
    float kraw = __bfloat162float(C1[off]);
    float uraw = __bfloat162float(C1[off + 2048]);
    float gin  = __bfloat162float(C1[off + 4096]);
    float a = (t == t0) ? a_first : sigmoidf_(kp);
    float sK = sigmoidf_(kraw);
    float u = uraw * sigmoidf_(gin) * (1.0f - sK);
    A *= a;
    U = a * U + u;
    kp = kraw;
  }
  int cidx = (b * NCHUNK + chunk) * STATE + ch;
  carryA[cidx] = A;
  carryU[cidx] = U;
}

// Pass B: exclusive scan of chunk carries along the chunk axis per channel.
__global__ __launch_bounds__(256) void carry_scan_kernel(
    const float* __restrict__ carryA, const float* __restrict__ carryU,
    float* __restrict__ carryIn) {
  int idx = blockIdx.x * 256 + threadIdx.x;  // b*STATE + ch
  int b = idx >> 11;
  int ch = idx & 2047;
  float h = 0.0f;
#pragma unroll
  for (int c = 0; c < NCHUNK; c++) {
    int cidx = (b * NCHUNK + c) * STATE + ch;
    carryIn[cidx] = h;
    h = carryA[cidx] * h + carryU[cidx];
  }
}

// Pass C: per-chunk local scan seeded with carryIn; writes h*sigmoid(g_out).
__global__ __launch_bounds__(256) void scan_chunk_kernel(
    const bf16* __restrict__ C1, const float* __restrict__ carryIn,
    bf16* __restrict__ out) {
  int b = blockIdx.x;              // batch 0..3
  int c0 = blockIdx.y * 32;        // channel base
  int chunk = blockIdx.z;
  int tstart = chunk * CHUNKL;
  __shared__ float a_s[32][65], u_s[32][65], h_s[32][65];
  int tid = threadIdx.x;
  int lane = tid & 63, wave = tid >> 6;
  int cc = tid & 31;   // channel within tile (load/store phases)
  int tq = tid >> 5;   // 0..7

  float carryH[8], carryK[8];
#pragma unroll
  for (int i = 0; i < 8; i++) {
    int ch = c0 + wave * 8 + i;
    carryH[i] = carryIn[(b * NCHUNK + chunk) * STATE + ch];
    carryK[i] = (chunk == 0)
                    ? 1.0f
                    : sigmoidf_(__bfloat162float(
                          C1[((long)(b * SEQ + tstart - 1)) * N1 + ch]));
  }

  float g_r[8];
  for (int t0 = tstart; t0 < tstart + CHUNKL; t0 += 64) {
    // load + gate: lanes along channels (coalesced rows); g_out stays in regs
#pragma unroll
    for (int i = 0; i < 8; i++) {
      int t = tq * 8 + i;
      long rowoff = ((long)(b * SEQ + t0 + t)) * N1 + c0 + cc;
      float kraw = __bfloat162float(C1[rowoff]);
      float uraw = __bfloat162float(C1[rowoff + 2048]);
      float gin  = __bfloat162float(C1[rowoff + 4096]);
      float gout = __bfloat162float(C1[rowoff + 6144]);
      float aK = sigmoidf_(kraw);
      a_s[cc][t] = aK;
      u_s[cc][t] = uraw * sigmoidf_(gin) * (1.0f - aK);
      g_r[i] = sigmoidf_(gout);
    }
    __syncthreads();
    // scan: each wave owns 8 channels; lane = time
#pragma unroll
    for (int i = 0; i < 8; i++) {
      int ch = wave * 8 + i;
      float aK = a_s[ch][lane];
      float u = u_s[ch][lane];
      float a = __shfl_up(aK, 1);     // a_t = K_{t-1}
      if (lane == 0) a = carryK[i];
      float A = a, U = u;
#pragma unroll
      for (int d = 1; d < 64; d <<= 1) {
        float Au = __shfl_up(A, d);
        float Uu = __shfl_up(U, d);
        if (lane >= d) { U += A * Uu; A *= Au; }
      }
      float h = U + A * carryH[i];
      carryH[i] = __shfl(h, 63);
      carryK[i] = __shfl(aK, 63);
      h_s[ch][lane] = h;
    }
    __syncthreads();
    // store: lanes along channels (coalesced); apply register-held g_out
#pragma unroll
    for (int i = 0; i < 8; i++) {
      int t = tq * 8 + i;
      out[((long)(b * SEQ + t0 + t)) * STATE + c0 + cc] =
          __float2bfloat16(h_s[cc][t] * g_r[i]);
    }
    __syncthreads();  // h_s consumed before next iter overwrites
  }
}

extern "C" void kernel_launch(void* const* d_in, const int* in_sizes, int n_in,
                              void* d_out, int out_size, void* d_ws, size_t ws_size,
                              hipStream_t stream) {
  const float* x    = (const float*)d_in[0];
  const float* ls   = (const float*)d_in[1];
  const float* rs   = (const float*)d_in[2];
  const float* ss   = (const float*)d_in[3];
  const float* Wk   = (const float*)d_in[4];
  const float* Wugg = (const float*)d_in[5];
  const float* Wout = (const float*)d_in[6];
  float* out = (float*)d_out;

  // workspace layout (~205.5 MB total)
  char* ws = (char*)d_ws;
  bf16* W1t = (bf16*)ws;                                   // [8192][1024] = Wk^T | Wugg^T
  bf16* W2t = (bf16*)(ws + 16777216);                      // [1024][2048] = Wout^T
  bf16* xn  = (bf16*)(ws + 16777216 + 4194304);            // [8192][1024]
  bf16* C1  = (bf16*)(ws + 16777216 + 4194304 + 16777216); // [8192][8192]
  bf16* sco = (bf16*)(ws + 16777216 + 4194304 + 16777216 + 134217728); // [8192][2048]
  // carry buffers (3 x 512 KB) overlay the xn region: xn is dead after GEMM1,
  // and the scan passes run strictly after GEMM1 in stream order.
  float* carryA  = (float*)xn;
  float* carryU  = carryA + BATCH * NCHUNK * STATE;
  float* carryIn = carryU + BATCH * NCHUNK * STATE;

  // weights -> bf16, transposed to [N][K]
  transpose_bf16_kernel<<<dim3(STATE / 32, DIMS / 32), 256, 0, stream>>>(Wk, W1t, DIMS, STATE);
  transpose_bf16_kernel<<<dim3(3 * STATE / 32, DIMS / 32), 256, 0, stream>>>(
      Wugg, W1t + (long)STATE * DIMS, DIMS, 3 * STATE);
  transpose_bf16_kernel<<<dim3(DIMS / 32, STATE / 32), 256, 0, stream>>>(Wout, W2t, STATE, DIMS);

  rmsnorm_kernel<<<TOKENS, 256, 0, stream>>>(x, ls, rs, ss, xn);

  gemm_bt<0><<<dim3(N1 / 128, TOKENS / 128), 256, 0, stream>>>(
      xn, W1t, (void*)C1, nullptr, TOKENS, N1, DIMS);

  chunk_summary_kernel<<<dim3(BATCH, STATE / 256, NCHUNK), 256, 0, stream>>>(
      C1, carryA, carryU);
  carry_scan_kernel<<<dim3(BATCH * STATE / 256), 256, 0, stream>>>(
      carryA, carryU, carryIn);
  scan_chunk_kernel<<<dim3(BATCH, STATE / 32, NCHUNK), 256, 0, stream>>>(
      C1, carryIn, sco);

  gemm_bt<1><<<dim3(DIMS / 128, TOKENS / 128), 256, 0, stream>>>(
      sco, W2t, (void*)out, x, TOKENS, DIMS, STATE);
}

// Round 4
// 472.657 us; speedup vs baseline: 1.0116x; 1.0116x over previous
//
#include <hip/hip_runtime.h>
#include <hip/hip_bf16.h>
#include <stdint.h>

#define DIMS 1024
#define STATE 2048
#define BATCH 4
#define SEQ 2048
#define TOKENS 8192   // BATCH*SEQ
#define N1 8192       // STATE + 3*STATE columns of fused GEMM1
#define NCHUNK 16
#define CHUNKL (SEQ / NCHUNK)   // 128

typedef __hip_bfloat16 bf16;
typedef __attribute__((ext_vector_type(8))) short bf16x8;
typedef __attribute__((ext_vector_type(4))) float f32x4;
typedef __attribute__((ext_vector_type(16))) float f32x16;

__device__ __forceinline__ float sigmoidf_(float x) {
  return 1.0f / (1.0f + __expf(-x));
}

// async global->LDS, 16B per lane. LDS dest must be wave-uniform base; HW does base + lane*16.
__device__ __forceinline__ void async_copy16(const void* g, void* l) {
  __builtin_amdgcn_global_load_lds(
      (const __attribute__((address_space(1))) void*)(uintptr_t)g,
      (__attribute__((address_space(3))) void*)(uint32_t)(uintptr_t)l,
      16, 0, 0);
}

// ---------------- weight transpose + fp32->bf16 cast: W[K][N] -> Wt[N][K] ----------------
__global__ __launch_bounds__(256) void transpose_bf16_kernel(
    const float* __restrict__ W, bf16* __restrict__ Wt, int K, int N) {
  __shared__ float tile[32][33];
  int tx = threadIdx.x & 31;
  int ty = threadIdx.x >> 5;  // 0..7
  long col = (long)blockIdx.x * 32 + tx;
  long rowb = (long)blockIdx.y * 32;
#pragma unroll
  for (int i = 0; i < 32; i += 8)
    tile[ty + i][tx] = W[(rowb + ty + i) * N + col];
  __syncthreads();
  long ocol = rowb + tx;                      // k index
  long orow = (long)blockIdx.x * 32 + ty;     // n index
#pragma unroll
  for (int i = 0; i < 32; i += 8)
    Wt[(orow + i) * K + ocol] = __float2bfloat16(tile[tx][ty + i]);
}

// ---------------- split RMSNorm -> bf16 ----------------
__global__ __launch_bounds__(256) void rmsnorm_kernel(
    const float* __restrict__ x, const float* __restrict__ ls,
    const float* __restrict__ rs, const float* __restrict__ ss,
    bf16* __restrict__ xn) {
  int token = blockIdx.x;
  int tid = threadIdx.x;  // 256 threads, 4 floats each
  const float4* xt = (const float4*)(x + (long)token * DIMS);
  float4 v = xt[tid];
  float s = v.x * v.x + v.y * v.y + v.z * v.z + v.w * v.w;
#pragma unroll
  for (int d = 32; d > 0; d >>= 1) s += __shfl_down(s, d);
  __shared__ float parts[4];
  if ((tid & 63) == 0) parts[tid >> 6] = s;
  __syncthreads();
  int j = tid * 4;
  bool left = j < 512;  // waves 0,1 cover elements 0..511
  float sum = left ? (parts[0] + parts[1]) : (parts[2] + parts[3]);
  float n = sqrtf(sum * (1.0f / 512.0f));  // ||v||*d^-1/2
  float inv = 1.0f / (n + 1e-8f);
  const float4* sc = (const float4*)(left ? ls : rs);
  float4 g = sc[left ? tid : tid - 128];
  float4 p = ((const float4*)ss)[tid];
  bf16* o = xn + (long)token * DIMS + j;
  o[0] = __float2bfloat16(v.x * g.x * inv * p.x);
  o[1] = __float2bfloat16(v.y * g.y * inv * p.y);
  o[2] = __float2bfloat16(v.z * g.z * inv * p.z);
  o[3] = __float2bfloat16(v.w * g.w * inv * p.w);
}

// ---------------- GEMM1: 256x128 block, 4 waves x (128x64) via 32x32x16 MFMA ----------------
// Rationale: LDS-BW-bound regime. Per block k-iter: 48 KB frag reads + 24 KB staging
// = 72 KB per 2.1 MFLOP (0.034 B/FLOP) vs 0.047 for the 128x128/16x16 structure.
// Operands swapped (mfma(b,a,acc)): D col(lane&31)=token, D row=channel
// = (reg&3)+8*(reg>>2)+4*(lane>>5) -> each reg-quad = 4 consecutive channels -> 8B stores.
__global__ __launch_bounds__(256, 2) void gemm1_big(
    const bf16* __restrict__ A, const bf16* __restrict__ Bt, bf16* __restrict__ C) {
  __shared__ __align__(16) bf16 As[256 * 32];  // 16 KB
  __shared__ __align__(16) bf16 Bs[128 * 32];  // 8 KB
  const int K = DIMS;
  int tid = threadIdx.x;
  int lane = tid & 63, wave = tid >> 6;
  int wm = wave & 1, wn = wave >> 1;  // wm: 128-row half, wn: 64-col half
  long arow0 = (long)blockIdx.y * 256;
  long brow0 = (long)blockIdx.x * 128;
  int m_lane = lane & 31, q4 = lane >> 5;  // frag row, k-half
  f32x16 acc[4][2] = {};  // [mt][nt]

  for (int k0 = 0; k0 < K; k0 += 32) {
    __syncthreads();  // prior iter's LDS reads done before overwrite
#pragma unroll
    for (int i = 0; i < 4; i++) {  // A: 1024 16B chunks, 4 per wave-instr group
      int c = (wave * 4 + i) * 64 + lane;
      int row = c >> 2, kc = c & 3;
      async_copy16(A + (arow0 + row) * K + k0 + kc * 8, (char*)As + (wave * 4 + i) * 1024);
    }
#pragma unroll
    for (int i = 0; i < 2; i++) {  // B: 512 chunks
      int c = (wave * 2 + i) * 64 + lane;
      int row = c >> 2, kc = c & 3;
      async_copy16(Bt + (brow0 + row) * K + k0 + kc * 8, (char*)Bs + (wave * 2 + i) * 1024);
    }
    __syncthreads();  // vmcnt(0) drained at barrier -> LDS visible
    const bf16x8* AsV = (const bf16x8*)As;
    const bf16x8* BsV = (const bf16x8*)Bs;
#pragma unroll
    for (int ks = 0; ks < 2; ks++) {
      bf16x8 af[4], bfr[2];
#pragma unroll
      for (int mt = 0; mt < 4; mt++)
        af[mt] = AsV[(wm * 128 + mt * 32 + m_lane) * 4 + ks * 2 + q4];
#pragma unroll
      for (int nt = 0; nt < 2; nt++)
        bfr[nt] = BsV[(wn * 64 + nt * 32 + m_lane) * 4 + ks * 2 + q4];
#pragma unroll
      for (int mt = 0; mt < 4; mt++)
#pragma unroll
        for (int nt = 0; nt < 2; nt++)
          acc[mt][nt] = __builtin_amdgcn_mfma_f32_32x32x16_bf16(bfr[nt], af[mt], acc[mt][nt], 0, 0, 0);
    }
  }
  // token = arow0 + wm*128 + mt*32 + m_lane; channel = brow0 + wn*64 + nt*32 + g*8 + q4*4 + j
#pragma unroll
  for (int mt = 0; mt < 4; mt++) {
    long row = arow0 + wm * 128 + mt * 32 + m_lane;
#pragma unroll
    for (int nt = 0; nt < 2; nt++) {
#pragma unroll
      for (int g = 0; g < 4; g++) {
        long col = brow0 + wn * 64 + nt * 32 + g * 8 + q4 * 4;
        bf16 tmp[4];
#pragma unroll
        for (int j = 0; j < 4; j++) tmp[j] = __float2bfloat16(acc[mt][nt][g * 4 + j]);
        *(uint2*)(C + row * N1 + col) = *(uint2*)tmp;
      }
    }
  }
}

// ---------------- m97-style GEMM (used for GEMM2): C[M,N] = A[M,K] @ Bt[N,K]^T ----------------
// Swapped operands -> lane holds 4 consecutive channels -> float4 residual epilogue.
template <int EPI>
__global__ __launch_bounds__(256) void gemm_bt(
    const bf16* __restrict__ A, const bf16* __restrict__ Bt,
    void* __restrict__ Cout, const float* __restrict__ resid,
    int M, int N, int K) {
  __shared__ __align__(16) bf16 As[128 * 32];
  __shared__ __align__(16) bf16 Bs[128 * 32];
  int tid = threadIdx.x;
  int lane = tid & 63, wave = tid >> 6;
  int wm = wave & 1, wn = wave >> 1;  // 2x2 wave grid, 64x64 each
  long arow0 = (long)blockIdx.y * 128;
  long brow0 = (long)blockIdx.x * 128;
  int r = lane & 15, q = lane >> 4;
  f32x4 acc[4][4] = {};

  for (int k0 = 0; k0 < K; k0 += 32) {
    __syncthreads();
#pragma unroll
    for (int i = 0; i < 2; i++) {
      int c = (wave * 2 + i) * 64 + lane;  // 16B chunk id, 0..511
      int row = c >> 2;
      int kp = (c & 3) * 8;
      async_copy16(A + (arow0 + row) * K + k0 + kp, (char*)As + (wave * 2 + i) * 1024);
      async_copy16(Bt + (brow0 + row) * K + k0 + kp, (char*)Bs + (wave * 2 + i) * 1024);
    }
    __syncthreads();
    const bf16x8* AsV = (const bf16x8*)As;
    const bf16x8* BsV = (const bf16x8*)Bs;
    bf16x8 af[4], bfr[4];
#pragma unroll
    for (int mt = 0; mt < 4; mt++) af[mt] = AsV[(wm * 64 + mt * 16 + r) * 4 + q];
#pragma unroll
    for (int nt = 0; nt < 4; nt++) bfr[nt] = BsV[(wn * 64 + nt * 16 + r) * 4 + q];
#pragma unroll
    for (int mt = 0; mt < 4; mt++)
#pragma unroll
      for (int nt = 0; nt < 4; nt++)
        acc[mt][nt] = __builtin_amdgcn_mfma_f32_16x16x32_bf16(bfr[nt], af[mt], acc[mt][nt], 0, 0, 0);
  }

  // Swapped C/D mapping: token = lane&15 (mt tile), channel = q*4+reg (nt tile).
  if (EPI == 0) {
    bf16* C = (bf16*)Cout;
#pragma unroll
    for (int mt = 0; mt < 4; mt++) {
      long row = arow0 + wm * 64 + mt * 16 + r;  // token
#pragma unroll
      for (int nt = 0; nt < 4; nt++) {
        long col = brow0 + wn * 64 + nt * 16 + q * 4;  // channel base
        bf16 tmp[4];
#pragma unroll
        for (int reg = 0; reg < 4; reg++) tmp[reg] = __float2bfloat16(acc[mt][nt][reg]);
        *(uint2*)(C + row * N + col) = *(uint2*)tmp;
      }
    }
  } else {
    float* C = (float*)Cout;
#pragma unroll
    for (int mt = 0; mt < 4; mt++) {
      long row = arow0 + wm * 64 + mt * 16 + r;  // token
#pragma unroll
      for (int nt = 0; nt < 4; nt++) {
        long col = brow0 + wn * 64 + nt * 16 + q * 4;  // channel base
        float4 rv = *(const float4*)(resid + row * N + col);
        float4 ov;
        ov.x = acc[mt][nt][0] + rv.x;
        ov.y = acc[mt][nt][1] + rv.y;
        ov.z = acc[mt][nt][2] + rv.z;
        ov.w = acc[mt][nt][3] + rv.w;
        *(float4*)(C + row * N + col) = ov;
      }
    }
  }
}

// ---------------- chunked gated linear scan ----------------
// h_t = a_t*h_{t-1} + u_t, a_t = sigmoid(Kraw_{t-1}) (a_0=1),
// u_t = uraw_t*sigmoid(gin_t)*(1-sigmoid(Kraw_t)). Chunk composes to h_out = A*h_in + U.

// Pass A: per (batch, channel, chunk) thread reduces the chunk to (A, U).
__global__ __launch_bounds__(256) void chunk_summary_kernel(
    const bf16* __restrict__ C1, float* __restrict__ carryA,
    float* __restrict__ carryU) {
  int b = blockIdx.x;
  int ch = blockIdx.y * 256 + threadIdx.x;
  int chunk = blockIdx.z;
  int t0 = chunk * CHUNKL;
  long base = ((long)b * SEQ) * N1 + ch;
  float kp = 0.0f;
  if (chunk != 0) kp = __bfloat162float(C1[base + (long)(t0 - 1) * N1]);
  float a_first = (chunk == 0) ? 1.0f : sigmoidf_(kp);
  float A = 1.0f, U = 0.0f;
#pragma unroll 8
  for (int t = t0; t < t0 + CHUNKL; t++) {
    long off = base + (long)t * N1;
    float kraw = __bfloat162float(C1[off]);
    float uraw = __bfloat162float(C1[off + 2048]);
    float gin  = __bfloat162float(C1[off + 4096]);
    float a = (t == t0) ? a_first : sigmoidf_(kp);
    float sK = sigmoidf_(kraw);
    float u = uraw * sigmoidf_(gin) * (1.0f - sK);
    A *= a;
    U = a * U + u;
    kp = kraw;
  }
  int cidx = (b * NCHUNK + chunk) * STATE + ch;
  carryA[cidx] = A;
  carryU[cidx] = U;
}

// Pass B: exclusive scan of chunk carries along the chunk axis per channel.
__global__ __launch_bounds__(256) void carry_scan_kernel(
    const float* __restrict__ carryA, const float* __restrict__ carryU,
    float* __restrict__ carryIn) {
  int idx = blockIdx.x * 256 + threadIdx.x;  // b*STATE + ch
  int b = idx >> 11;
  int ch = idx & 2047;
  float h = 0.0f;
#pragma unroll
  for (int c = 0; c < NCHUNK; c++) {
    int cidx = (b * NCHUNK + c) * STATE + ch;
    carryIn[cidx] = h;
    h = carryA[cidx] * h + carryU[cidx];
  }
}

// Pass C: per-chunk local scan seeded with carryIn; writes h*sigmoid(g_out).
__global__ __launch_bounds__(256) void scan_chunk_kernel(
    const bf16* __restrict__ C1, const float* __restrict__ carryIn,
    bf16* __restrict__ out) {
  int b = blockIdx.x;              // batch 0..3
  int c0 = blockIdx.y * 32;        // channel base
  int chunk = blockIdx.z;
  int tstart = chunk * CHUNKL;
  __shared__ float a_s[32][65], u_s[32][65], h_s[32][65];
  int tid = threadIdx.x;
  int lane = tid & 63, wave = tid >> 6;
  int cc = tid & 31;   // channel within tile (load/store phases)
  int tq = tid >> 5;   // 0..7

  float carryH[8], carryK[8];
#pragma unroll
  for (int i = 0; i < 8; i++) {
    int ch = c0 + wave * 8 + i;
    carryH[i] = carryIn[(b * NCHUNK + chunk) * STATE + ch];
    carryK[i] = (chunk == 0)
                    ? 1.0f
                    : sigmoidf_(__bfloat162float(
                          C1[((long)(b * SEQ + tstart - 1)) * N1 + ch]));
  }

  float g_r[8];
  for (int t0 = tstart; t0 < tstart + CHUNKL; t0 += 64) {
#pragma unroll
    for (int i = 0; i < 8; i++) {
      int t = tq * 8 + i;
      long rowoff = ((long)(b * SEQ + t0 + t)) * N1 + c0 + cc;
      float kraw = __bfloat162float(C1[rowoff]);
      float uraw = __bfloat162float(C1[rowoff + 2048]);
      float gin  = __bfloat162float(C1[rowoff + 4096]);
      float gout = __bfloat162float(C1[rowoff + 6144]);
      float aK = sigmoidf_(kraw);
      a_s[cc][t] = aK;
      u_s[cc][t] = uraw * sigmoidf_(gin) * (1.0f - aK);
      g_r[i] = sigmoidf_(gout);
    }
    __syncthreads();
#pragma unroll
    for (int i = 0; i < 8; i++) {
      int ch = wave * 8 + i;
      float aK = a_s[ch][lane];
      float u = u_s[ch][lane];
      float a = __shfl_up(aK, 1);     // a_t = K_{t-1}
      if (lane == 0) a = carryK[i];
      float A = a, U = u;
#pragma unroll
      for (int d = 1; d < 64; d <<= 1) {
        float Au = __shfl_up(A, d);
        float Uu = __shfl_up(U, d);
        if (lane >= d) { U += A * Uu; A *= Au; }
      }
      float h = U + A * carryH[i];
      carryH[i] = __shfl(h, 63);
      carryK[i] = __shfl(aK, 63);
      h_s[ch][lane] = h;
    }
    __syncthreads();
#pragma unroll
    for (int i = 0; i < 8; i++) {
      int t = tq * 8 + i;
      out[((long)(b * SEQ + t0 + t)) * STATE + c0 + cc] =
          __float2bfloat16(h_s[cc][t] * g_r[i]);
    }
    __syncthreads();
  }
}

extern "C" void kernel_launch(void* const* d_in, const int* in_sizes, int n_in,
                              void* d_out, int out_size, void* d_ws, size_t ws_size,
                              hipStream_t stream) {
  const float* x    = (const float*)d_in[0];
  const float* ls   = (const float*)d_in[1];
  const float* rs   = (const float*)d_in[2];
  const float* ss   = (const float*)d_in[3];
  const float* Wk   = (const float*)d_in[4];
  const float* Wugg = (const float*)d_in[5];
  const float* Wout = (const float*)d_in[6];
  float* out = (float*)d_out;

  // workspace layout (~205.5 MB total)
  char* ws = (char*)d_ws;
  bf16* W1t = (bf16*)ws;                                   // [8192][1024] = Wk^T | Wugg^T
  bf16* W2t = (bf16*)(ws + 16777216);                      // [1024][2048] = Wout^T
  bf16* xn  = (bf16*)(ws + 16777216 + 4194304);            // [8192][1024]
  bf16* C1  = (bf16*)(ws + 16777216 + 4194304 + 16777216); // [8192][8192]
  bf16* sco = (bf16*)(ws + 16777216 + 4194304 + 16777216 + 134217728); // [8192][2048]
  // carry buffers (3 x 512 KB) overlay the xn region: xn is dead after GEMM1.
  float* carryA  = (float*)xn;
  float* carryU  = carryA + BATCH * NCHUNK * STATE;
  float* carryIn = carryU + BATCH * NCHUNK * STATE;

  // weights -> bf16, transposed to [N][K]
  transpose_bf16_kernel<<<dim3(STATE / 32, DIMS / 32), 256, 0, stream>>>(Wk, W1t, DIMS, STATE);
  transpose_bf16_kernel<<<dim3(3 * STATE / 32, DIMS / 32), 256, 0, stream>>>(
      Wugg, W1t + (long)STATE * DIMS, DIMS, 3 * STATE);
  transpose_bf16_kernel<<<dim3(DIMS / 32, STATE / 32), 256, 0, stream>>>(Wout, W2t, STATE, DIMS);

  rmsnorm_kernel<<<TOKENS, 256, 0, stream>>>(x, ls, rs, ss, xn);

  gemm1_big<<<dim3(N1 / 128, TOKENS / 256), 256, 0, stream>>>(xn, W1t, C1);

  chunk_summary_kernel<<<dim3(BATCH, STATE / 256, NCHUNK), 256, 0, stream>>>(
      C1, carryA, carryU);
  carry_scan_kernel<<<dim3(BATCH * STATE / 256), 256, 0, stream>>>(
      carryA, carryU, carryIn);
  scan_chunk_kernel<<<dim3(BATCH, STATE / 32, NCHUNK), 256, 0, stream>>>(
      C1, carryIn, sco);

  gemm_bt<1><<<dim3(DIMS / 128, TOKENS / 128), 256, 0, stream>>>(
      sco, W2t, (void*)out, x, TOKENS, DIMS, STATE);
}

// Round 5
// 453.323 us; speedup vs baseline: 1.0547x; 1.0427x over previous
//
#include <hip/hip_runtime.h>
#include <hip/hip_bf16.h>
#include <stdint.h>

#define DIMS 1024
#define STATE 2048
#define BATCH 4
#define SEQ 2048
#define TOKENS 8192   // BATCH*SEQ
#define N1 8192       // STATE + 3*STATE columns of fused GEMM1
#define NCHUNK 16
#define CHUNKL (SEQ / NCHUNK)   // 128

typedef __hip_bfloat16 bf16;
typedef __attribute__((ext_vector_type(8))) short bf16x8;
typedef __attribute__((ext_vector_type(4))) float f32x4;
typedef __attribute__((ext_vector_type(16))) float f32x16;

__device__ __forceinline__ float sigmoidf_(float x) {
  return 1.0f / (1.0f + __expf(-x));
}

// async global->LDS, 16B per lane. LDS dest must be wave-uniform base; HW does base + lane*16.
__device__ __forceinline__ void async_copy16(const void* g, void* l) {
  __builtin_amdgcn_global_load_lds(
      (const __attribute__((address_space(1))) void*)(uintptr_t)g,
      (__attribute__((address_space(3))) void*)(uint32_t)(uintptr_t)l,
      16, 0, 0);
}

// ---- LDS XOR swizzle (tiles of R rows x 32 bf16 = 4 x 16B chunks per row) ----
// Bank period is 128 B = one row-pair. Physical chunk:
//   line = row>>1, sub = (row&1)*4 + kc, p = line*8 + (sub ^ (line&7)).
// Reading a column of rows (stride 64 B) then spreads uniformly over all 8
// chunk columns -> dense LDS access (was: all lanes on one 4-bank column).
__device__ __forceinline__ int swz_chunk(int row, int kc) {
  int line = row >> 1;
  int sub = ((row & 1) << 2) | kc;
  return (line << 3) | (sub ^ (line & 7));
}
// staging inverse: LDS chunk c -> (row, kc) of the global source
__device__ __forceinline__ void swz_decode(int c, int& row, int& kc) {
  int line = c >> 3;
  int sub = (c & 7) ^ (line & 7);
  row = (line << 1) | (sub >> 2);
  kc = sub & 3;
}

// ---------------- weight transpose + fp32->bf16 cast: W[K][N] -> Wt[N][K] ----------------
__global__ __launch_bounds__(256) void transpose_bf16_kernel(
    const float* __restrict__ W, bf16* __restrict__ Wt, int K, int N) {
  __shared__ float tile[32][33];
  int tx = threadIdx.x & 31;
  int ty = threadIdx.x >> 5;  // 0..7
  long col = (long)blockIdx.x * 32 + tx;
  long rowb = (long)blockIdx.y * 32;
#pragma unroll
  for (int i = 0; i < 32; i += 8)
    tile[ty + i][tx] = W[(rowb + ty + i) * N + col];
  __syncthreads();
  long ocol = rowb + tx;                      // k index
  long orow = (long)blockIdx.x * 32 + ty;     // n index
#pragma unroll
  for (int i = 0; i < 32; i += 8)
    Wt[(orow + i) * K + ocol] = __float2bfloat16(tile[tx][ty + i]);
}

// ---------------- split RMSNorm -> bf16 ----------------
__global__ __launch_bounds__(256) void rmsnorm_kernel(
    const float* __restrict__ x, const float* __restrict__ ls,
    const float* __restrict__ rs, const float* __restrict__ ss,
    bf16* __restrict__ xn) {
  int token = blockIdx.x;
  int tid = threadIdx.x;  // 256 threads, 4 floats each
  const float4* xt = (const float4*)(x + (long)token * DIMS);
  float4 v = xt[tid];
  float s = v.x * v.x + v.y * v.y + v.z * v.z + v.w * v.w;
#pragma unroll
  for (int d = 32; d > 0; d >>= 1) s += __shfl_down(s, d);
  __shared__ float parts[4];
  if ((tid & 63) == 0) parts[tid >> 6] = s;
  __syncthreads();
  int j = tid * 4;
  bool left = j < 512;  // waves 0,1 cover elements 0..511
  float sum = left ? (parts[0] + parts[1]) : (parts[2] + parts[3]);
  float n = sqrtf(sum * (1.0f / 512.0f));  // ||v||*d^-1/2
  float inv = 1.0f / (n + 1e-8f);
  const float4* sc = (const float4*)(left ? ls : rs);
  float4 g = sc[left ? tid : tid - 128];
  float4 p = ((const float4*)ss)[tid];
  bf16* o = xn + (long)token * DIMS + j;
  o[0] = __float2bfloat16(v.x * g.x * inv * p.x);
  o[1] = __float2bfloat16(v.y * g.y * inv * p.y);
  o[2] = __float2bfloat16(v.z * g.z * inv * p.z);
  o[3] = __float2bfloat16(v.w * g.w * inv * p.w);
}

// ---------------- GEMM1: 256x128 block, 4 waves x (128x64) via 32x32x16 MFMA ----------------
// Operands swapped (mfma(b,a,acc)): D col(lane&31)=token, D row=channel -> 8B stores.
// LDS layout XOR-swizzled (see swz_chunk) to kill the 64B-row-stride bank aliasing.
__global__ __launch_bounds__(256, 2) void gemm1_big(
    const bf16* __restrict__ A, const bf16* __restrict__ Bt, bf16* __restrict__ C) {
  __shared__ __align__(16) bf16 As[256 * 32];  // 16 KB
  __shared__ __align__(16) bf16 Bs[128 * 32];  // 8 KB
  const int K = DIMS;
  int tid = threadIdx.x;
  int lane = tid & 63, wave = tid >> 6;
  int wm = wave & 1, wn = wave >> 1;  // wm: 128-row half, wn: 64-col half
  long arow0 = (long)blockIdx.y * 256;
  long brow0 = (long)blockIdx.x * 128;
  int m_lane = lane & 31, q4 = lane >> 5;  // frag row, k-half
  f32x16 acc[4][2] = {};  // [mt][nt]

  for (int k0 = 0; k0 < K; k0 += 32) {
    __syncthreads();  // prior iter's LDS reads done before overwrite
#pragma unroll
    for (int i = 0; i < 4; i++) {  // A: 1024 16B chunks
      int c = (wave * 4 + i) * 64 + lane;
      int row, kc; swz_decode(c, row, kc);
      async_copy16(A + (arow0 + row) * K + k0 + kc * 8, (char*)As + (wave * 4 + i) * 1024);
    }
#pragma unroll
    for (int i = 0; i < 2; i++) {  // B: 512 chunks
      int c = (wave * 2 + i) * 64 + lane;
      int row, kc; swz_decode(c, row, kc);
      async_copy16(Bt + (brow0 + row) * K + k0 + kc * 8, (char*)Bs + (wave * 2 + i) * 1024);
    }
    __syncthreads();  // vmcnt(0) drained at barrier -> LDS visible
    const bf16x8* AsV = (const bf16x8*)As;
    const bf16x8* BsV = (const bf16x8*)Bs;
#pragma unroll
    for (int ks = 0; ks < 2; ks++) {
      bf16x8 af[4], bfr[2];
#pragma unroll
      for (int mt = 0; mt < 4; mt++)
        af[mt] = AsV[swz_chunk(wm * 128 + mt * 32 + m_lane, ks * 2 + q4)];
#pragma unroll
      for (int nt = 0; nt < 2; nt++)
        bfr[nt] = BsV[swz_chunk(wn * 64 + nt * 32 + m_lane, ks * 2 + q4)];
#pragma unroll
      for (int mt = 0; mt < 4; mt++)
#pragma unroll
        for (int nt = 0; nt < 2; nt++)
          acc[mt][nt] = __builtin_amdgcn_mfma_f32_32x32x16_bf16(bfr[nt], af[mt], acc[mt][nt], 0, 0, 0);
    }
  }
  // token = arow0 + wm*128 + mt*32 + m_lane; channel = brow0 + wn*64 + nt*32 + g*8 + q4*4 + j
#pragma unroll
  for (int mt = 0; mt < 4; mt++) {
    long row = arow0 + wm * 128 + mt * 32 + m_lane;
#pragma unroll
    for (int nt = 0; nt < 2; nt++) {
#pragma unroll
      for (int g = 0; g < 4; g++) {
        long col = brow0 + wn * 64 + nt * 32 + g * 8 + q4 * 4;
        bf16 tmp[4];
#pragma unroll
        for (int j = 0; j < 4; j++) tmp[j] = __float2bfloat16(acc[mt][nt][g * 4 + j]);
        *(uint2*)(C + row * N1 + col) = *(uint2*)tmp;
      }
    }
  }
}

// ---------------- m97-style GEMM (GEMM2): C[M,N] = A[M,K] @ Bt[N,K]^T ----------------
// Swapped operands -> lane holds 4 consecutive channels -> float4 residual epilogue.
// LDS XOR-swizzled like gemm1_big.
template <int EPI>
__global__ __launch_bounds__(256) void gemm_bt(
    const bf16* __restrict__ A, const bf16* __restrict__ Bt,
    void* __restrict__ Cout, const float* __restrict__ resid,
    int M, int N, int K) {
  __shared__ __align__(16) bf16 As[128 * 32];
  __shared__ __align__(16) bf16 Bs[128 * 32];
  int tid = threadIdx.x;
  int lane = tid & 63, wave = tid >> 6;
  int wm = wave & 1, wn = wave >> 1;  // 2x2 wave grid, 64x64 each
  long arow0 = (long)blockIdx.y * 128;
  long brow0 = (long)blockIdx.x * 128;
  int r = lane & 15, q = lane >> 4;
  f32x4 acc[4][4] = {};

  for (int k0 = 0; k0 < K; k0 += 32) {
    __syncthreads();
#pragma unroll
    for (int i = 0; i < 2; i++) {
      int c = (wave * 2 + i) * 64 + lane;  // 16B chunk id, 0..511
      int row, kc; swz_decode(c, row, kc);
      async_copy16(A + (arow0 + row) * K + k0 + kc * 8, (char*)As + (wave * 2 + i) * 1024);
      async_copy16(Bt + (brow0 + row) * K + k0 + kc * 8, (char*)Bs + (wave * 2 + i) * 1024);
    }
    __syncthreads();
    const bf16x8* AsV = (const bf16x8*)As;
    const bf16x8* BsV = (const bf16x8*)Bs;
    bf16x8 af[4], bfr[4];
#pragma unroll
    for (int mt = 0; mt < 4; mt++) af[mt] = AsV[swz_chunk(wm * 64 + mt * 16 + r, q)];
#pragma unroll
    for (int nt = 0; nt < 4; nt++) bfr[nt] = BsV[swz_chunk(wn * 64 + nt * 16 + r, q)];
#pragma unroll
    for (int mt = 0; mt < 4; mt++)
#pragma unroll
      for (int nt = 0; nt < 4; nt++)
        acc[mt][nt] = __builtin_amdgcn_mfma_f32_16x16x32_bf16(bfr[nt], af[mt], acc[mt][nt], 0, 0, 0);
  }

  // Swapped C/D mapping: token = lane&15 (mt tile), channel = q*4+reg (nt tile).
  if (EPI == 0) {
    bf16* C = (bf16*)Cout;
#pragma unroll
    for (int mt = 0; mt < 4; mt++) {
      long row = arow0 + wm * 64 + mt * 16 + r;  // token
#pragma unroll
      for (int nt = 0; nt < 4; nt++) {
        long col = brow0 + wn * 64 + nt * 16 + q * 4;  // channel base
        bf16 tmp[4];
#pragma unroll
        for (int reg = 0; reg < 4; reg++) tmp[reg] = __float2bfloat16(acc[mt][nt][reg]);
        *(uint2*)(C + row * N + col) = *(uint2*)tmp;
      }
    }
  } else {
    float* C = (float*)Cout;
#pragma unroll
    for (int mt = 0; mt < 4; mt++) {
      long row = arow0 + wm * 64 + mt * 16 + r;  // token
#pragma unroll
      for (int nt = 0; nt < 4; nt++) {
        long col = brow0 + wn * 64 + nt * 16 + q * 4;  // channel base
        float4 rv = *(const float4*)(resid + row * N + col);
        float4 ov;
        ov.x = acc[mt][nt][0] + rv.x;
        ov.y = acc[mt][nt][1] + rv.y;
        ov.z = acc[mt][nt][2] + rv.z;
        ov.w = acc[mt][nt][3] + rv.w;
        *(float4*)(C + row * N + col) = ov;
      }
    }
  }
}

// ---------------- chunked gated linear scan ----------------
// h_t = a_t*h_{t-1} + u_t, a_t = sigmoid(Kraw_{t-1}) (a_0=1),
// u_t = uraw_t*sigmoid(gin_t)*(1-sigmoid(Kraw_t)). Chunk composes to h_out = A*h_in + U.

// Pass A: per (batch, channel, chunk) thread reduces the chunk to (A, U).
__global__ __launch_bounds__(256) void chunk_summary_kernel(
    const bf16* __restrict__ C1, float* __restrict__ carryA,
    float* __restrict__ carryU) {
  int b = blockIdx.x;
  int ch = blockIdx.y * 256 + threadIdx.x;
  int chunk = blockIdx.z;
  int t0 = chunk * CHUNKL;
  long base = ((long)b * SEQ) * N1 + ch;
  float kp = 0.0f;
  if (chunk != 0) kp = __bfloat162float(C1[base + (long)(t0 - 1) * N1]);
  float a_first = (chunk == 0) ? 1.0f : sigmoidf_(kp);
  float A = 1.0f, U = 0.0f;
#pragma unroll 8
  for (int t = t0; t < t0 + CHUNKL; t++) {
    long off = base + (long)t * N1;
    float kraw = __bfloat162float(C1[off]);
    float uraw = __bfloat162float(C1[off + 2048]);
    float gin  = __bfloat162float(C1[off + 4096]);
    float a = (t == t0) ? a_first : sigmoidf_(kp);
    float sK = sigmoidf_(kraw);
    float u = uraw * sigmoidf_(gin) * (1.0f - sK);
    A *= a;
    U = a * U + u;
    kp = kraw;
  }
  int cidx = (b * NCHUNK + chunk) * STATE + ch;
  carryA[cidx] = A;
  carryU[cidx] = U;
}

// Pass B: exclusive scan of chunk carries along the chunk axis per channel.
__global__ __launch_bounds__(256) void carry_scan_kernel(
    const float* __restrict__ carryA, const float* __restrict__ carryU,
    float* __restrict__ carryIn) {
  int idx = blockIdx.x * 256 + threadIdx.x;  // b*STATE + ch
  int b = idx >> 11;
  int ch = idx & 2047;
  float h = 0.0f;
#pragma unroll
  for (int c = 0; c < NCHUNK; c++) {
    int cidx = (b * NCHUNK + c) * STATE + ch;
    carryIn[cidx] = h;
    h = carryA[cidx] * h + carryU[cidx];
  }
}

// Pass C: per-chunk local scan seeded with carryIn; writes h*sigmoid(g_out).
__global__ __launch_bounds__(256) void scan_chunk_kernel(
    const bf16* __restrict__ C1, const float* __restrict__ carryIn,
    bf16* __restrict__ out) {
  int b = blockIdx.x;              // batch 0..3
  int c0 = blockIdx.y * 32;        // channel base
  int chunk = blockIdx.z;
  int tstart = chunk * CHUNKL;
  __shared__ float a_s[32][65], u_s[32][65], h_s[32][65];
  int tid = threadIdx.x;
  int lane = tid & 63, wave = tid >> 6;
  int cc = tid & 31;   // channel within tile (load/store phases)
  int tq = tid >> 5;   // 0..7

  float carryH[8], carryK[8];
#pragma unroll
  for (int i = 0; i < 8; i++) {
    int ch = c0 + wave * 8 + i;
    carryH[i] = carryIn[(b * NCHUNK + chunk) * STATE + ch];
    carryK[i] = (chunk == 0)
                    ? 1.0f
                    : sigmoidf_(__bfloat162float(
                          C1[((long)(b * SEQ + tstart - 1)) * N1 + ch]));
  }

  float g_r[8];
  for (int t0 = tstart; t0 < tstart + CHUNKL; t0 += 64) {
#pragma unroll
    for (int i = 0; i < 8; i++) {
      int t = tq * 8 + i;
      long rowoff = ((long)(b * SEQ + t0 + t)) * N1 + c0 + cc;
      float kraw = __bfloat162float(C1[rowoff]);
      float uraw = __bfloat162float(C1[rowoff + 2048]);
      float gin  = __bfloat162float(C1[rowoff + 4096]);
      float gout = __bfloat162float(C1[rowoff + 6144]);
      float aK = sigmoidf_(kraw);
      a_s[cc][t] = aK;
      u_s[cc][t] = uraw * sigmoidf_(gin) * (1.0f - aK);
      g_r[i] = sigmoidf_(gout);
    }
    __syncthreads();
#pragma unroll
    for (int i = 0; i < 8; i++) {
      int ch = wave * 8 + i;
      float aK = a_s[ch][lane];
      float u = u_s[ch][lane];
      float a = __shfl_up(aK, 1);     // a_t = K_{t-1}
      if (lane == 0) a = carryK[i];
      float A = a, U = u;
#pragma unroll
      for (int d = 1; d < 64; d <<= 1) {
        float Au = __shfl_up(A, d);
        float Uu = __shfl_up(U, d);
        if (lane >= d) { U += A * Uu; A *= Au; }
      }
      float h = U + A * carryH[i];
      carryH[i] = __shfl(h, 63);
      carryK[i] = __shfl(aK, 63);
      h_s[ch][lane] = h;
    }
    __syncthreads();
#pragma unroll
    for (int i = 0; i < 8; i++) {
      int t = tq * 8 + i;
      out[((long)(b * SEQ + t0 + t)) * STATE + c0 + cc] =
          __float2bfloat16(h_s[cc][t] * g_r[i]);
    }
    __syncthreads();
  }
}

extern "C" void kernel_launch(void* const* d_in, const int* in_sizes, int n_in,
                              void* d_out, int out_size, void* d_ws, size_t ws_size,
                              hipStream_t stream) {
  const float* x    = (const float*)d_in[0];
  const float* ls   = (const float*)d_in[1];
  const float* rs   = (const float*)d_in[2];
  const float* ss   = (const float*)d_in[3];
  const float* Wk   = (const float*)d_in[4];
  const float* Wugg = (const float*)d_in[5];
  const float* Wout = (const float*)d_in[6];
  float* out = (float*)d_out;

  // workspace layout (~205.5 MB total)
  char* ws = (char*)d_ws;
  bf16* W1t = (bf16*)ws;                                   // [8192][1024] = Wk^T | Wugg^T
  bf16* W2t = (bf16*)(ws + 16777216);                      // [1024][2048] = Wout^T
  bf16* xn  = (bf16*)(ws + 16777216 + 4194304);            // [8192][1024]
  bf16* C1  = (bf16*)(ws + 16777216 + 4194304 + 16777216); // [8192][8192]
  bf16* sco = (bf16*)(ws + 16777216 + 4194304 + 16777216 + 134217728); // [8192][2048]
  // carry buffers (3 x 512 KB) overlay the xn region: xn is dead after GEMM1.
  float* carryA  = (float*)xn;
  float* carryU  = carryA + BATCH * NCHUNK * STATE;
  float* carryIn = carryU + BATCH * NCHUNK * STATE;

  // weights -> bf16, transposed to [N][K]
  transpose_bf16_kernel<<<dim3(STATE / 32, DIMS / 32), 256, 0, stream>>>(Wk, W1t, DIMS, STATE);
  transpose_bf16_kernel<<<dim3(3 * STATE / 32, DIMS / 32), 256, 0, stream>>>(
      Wugg, W1t + (long)STATE * DIMS, DIMS, 3 * STATE);
  transpose_bf16_kernel<<<dim3(DIMS / 32, STATE / 32), 256, 0, stream>>>(Wout, W2t, STATE, DIMS);

  rmsnorm_kernel<<<TOKENS, 256, 0, stream>>>(x, ls, rs, ss, xn);

  gemm1_big<<<dim3(N1 / 128, TOKENS / 256), 256, 0, stream>>>(xn, W1t, C1);

  chunk_summary_kernel<<<dim3(BATCH, STATE / 256, NCHUNK), 256, 0, stream>>>(
      C1, carryA, carryU);
  carry_scan_kernel<<<dim3(BATCH * STATE / 256), 256, 0, stream>>>(
      carryA, carryU, carryIn);
  scan_chunk_kernel<<<dim3(BATCH, STATE / 32, NCHUNK), 256, 0, stream>>>(
      C1, carryIn, sco);

  gemm_bt<1><<<dim3(DIMS / 128, TOKENS / 128), 256, 0, stream>>>(
      sco, W2t, (void*)out, x, TOKENS, DIMS, STATE);
}

// Round 6
// 445.624 us; speedup vs baseline: 1.0730x; 1.0173x over previous
//
#include <hip/hip_runtime.h>
#include <hip/hip_bf16.h>
#include <stdint.h>

#define DIMS 1024
#define STATE 2048
#define BATCH 4
#define SEQ 2048
#define TOKENS 8192   // BATCH*SEQ
#define N1 8192       // STATE + 3*STATE columns of fused GEMM1
#define NCHUNK 16
#define CHUNKL (SEQ / NCHUNK)   // 128

typedef __hip_bfloat16 bf16;
typedef __attribute__((ext_vector_type(8))) short bf16x8;
typedef __attribute__((ext_vector_type(4))) float f32x4;
typedef __attribute__((ext_vector_type(16))) float f32x16;

__device__ __forceinline__ float sigmoidf_(float x) {
  return 1.0f / (1.0f + __expf(-x));
}

// async global->LDS, 16B per lane. LDS dest must be wave-uniform base; HW does base + lane*16.
__device__ __forceinline__ void async_copy16(const void* g, void* l) {
  __builtin_amdgcn_global_load_lds(
      (const __attribute__((address_space(1))) void*)(uintptr_t)g,
      (__attribute__((address_space(3))) void*)(uint32_t)(uintptr_t)l,
      16, 0, 0);
}

// ---- LDS XOR swizzle for 64-bf16 (128 B) rows: one row == one bank period ----
// Physical 16B-chunk index within tile: p = row*8 + (kc ^ (row&7)).
// A column read (fixed kc, rows varying) then sweeps all 8 chunk columns
// uniformly -> dense LDS access.
__device__ __forceinline__ int swz64(int row, int kc) {
  return (row << 3) | (kc ^ (row & 7));
}
// staging inverse: linear chunk c -> (row, source kc)
__device__ __forceinline__ void swz64_dec(int c, int& row, int& kc) {
  row = c >> 3;
  kc = (c & 7) ^ (row & 7);
}

// ---------------- weight transpose + fp32->bf16 cast: W[K][N] -> Wt[N][K] ----------------
__global__ __launch_bounds__(256) void transpose_bf16_kernel(
    const float* __restrict__ W, bf16* __restrict__ Wt, int K, int N) {
  __shared__ float tile[32][33];
  int tx = threadIdx.x & 31;
  int ty = threadIdx.x >> 5;  // 0..7
  long col = (long)blockIdx.x * 32 + tx;
  long rowb = (long)blockIdx.y * 32;
#pragma unroll
  for (int i = 0; i < 32; i += 8)
    tile[ty + i][tx] = W[(rowb + ty + i) * N + col];
  __syncthreads();
  long ocol = rowb + tx;                      // k index
  long orow = (long)blockIdx.x * 32 + ty;     // n index
#pragma unroll
  for (int i = 0; i < 32; i += 8)
    Wt[(orow + i) * K + ocol] = __float2bfloat16(tile[tx][ty + i]);
}

// ---------------- split RMSNorm -> bf16 ----------------
__global__ __launch_bounds__(256) void rmsnorm_kernel(
    const float* __restrict__ x, const float* __restrict__ ls,
    const float* __restrict__ rs, const float* __restrict__ ss,
    bf16* __restrict__ xn) {
  int token = blockIdx.x;
  int tid = threadIdx.x;  // 256 threads, 4 floats each
  const float4* xt = (const float4*)(x + (long)token * DIMS);
  float4 v = xt[tid];
  float s = v.x * v.x + v.y * v.y + v.z * v.z + v.w * v.w;
#pragma unroll
  for (int d = 32; d > 0; d >>= 1) s += __shfl_down(s, d);
  __shared__ float parts[4];
  if ((tid & 63) == 0) parts[tid >> 6] = s;
  __syncthreads();
  int j = tid * 4;
  bool left = j < 512;  // waves 0,1 cover elements 0..511
  float sum = left ? (parts[0] + parts[1]) : (parts[2] + parts[3]);
  float n = sqrtf(sum * (1.0f / 512.0f));  // ||v||*d^-1/2
  float inv = 1.0f / (n + 1e-8f);
  const float4* sc = (const float4*)(left ? ls : rs);
  float4 g = sc[left ? tid : tid - 128];
  float4 p = ((const float4*)ss)[tid];
  bf16* o = xn + (long)token * DIMS + j;
  o[0] = __float2bfloat16(v.x * g.x * inv * p.x);
  o[1] = __float2bfloat16(v.y * g.y * inv * p.y);
  o[2] = __float2bfloat16(v.z * g.z * inv * p.z);
  o[3] = __float2bfloat16(v.w * g.w * inv * p.w);
}

// ---------------- GEMM1: 256x128 block, BK=64, 4 waves x (128x64) via 32x32x16 MFMA ----
// BK=64 halves the number of k-iterations (16 for K=1024) and thus the number of
// full vmcnt(0)+barrier drains, the dominant stall at BK=32 (MfmaUtil 32%).
// Operands swapped (mfma(b,a,acc)): D col(lane&31)=token, D row=channel -> 8B stores.
__global__ __launch_bounds__(256, 2) void gemm1_big(
    const bf16* __restrict__ A, const bf16* __restrict__ Bt, bf16* __restrict__ C) {
  __shared__ __align__(16) bf16 As[256 * 64];  // 32 KB
  __shared__ __align__(16) bf16 Bs[128 * 64];  // 16 KB
  const int K = DIMS;
  int tid = threadIdx.x;
  int lane = tid & 63, wave = tid >> 6;
  int wm = wave & 1, wn = wave >> 1;  // wm: 128-row half, wn: 64-col half
  long arow0 = (long)blockIdx.y * 256;
  long brow0 = (long)blockIdx.x * 128;
  int m_lane = lane & 31, q4 = lane >> 5;  // frag row, k-half within 32-slice
  f32x16 acc[4][2] = {};  // [mt][nt]

  for (int k0 = 0; k0 < K; k0 += 64) {
    __syncthreads();  // prior iter's LDS reads done before overwrite
#pragma unroll
    for (int i = 0; i < 8; i++) {  // A: 2048 16B chunks
      int c = (wave * 8 + i) * 64 + lane;
      int row, kc; swz64_dec(c, row, kc);
      async_copy16(A + (arow0 + row) * K + k0 + kc * 8, (char*)As + (wave * 8 + i) * 1024);
    }
#pragma unroll
    for (int i = 0; i < 4; i++) {  // B: 1024 chunks
      int c = (wave * 4 + i) * 64 + lane;
      int row, kc; swz64_dec(c, row, kc);
      async_copy16(Bt + (brow0 + row) * K + k0 + kc * 8, (char*)Bs + (wave * 4 + i) * 1024);
    }
    __syncthreads();  // vmcnt(0) drained at barrier -> LDS visible
    const bf16x8* AsV = (const bf16x8*)As;
    const bf16x8* BsV = (const bf16x8*)Bs;
#pragma unroll
    for (int ks = 0; ks < 4; ks++) {  // four 16-element k-slices
      int kc = ks * 2 + q4;
      bf16x8 af[4], bfr[2];
#pragma unroll
      for (int mt = 0; mt < 4; mt++)
        af[mt] = AsV[swz64(wm * 128 + mt * 32 + m_lane, kc)];
#pragma unroll
      for (int nt = 0; nt < 2; nt++)
        bfr[nt] = BsV[swz64(wn * 64 + nt * 32 + m_lane, kc)];
#pragma unroll
      for (int mt = 0; mt < 4; mt++)
#pragma unroll
        for (int nt = 0; nt < 2; nt++)
          acc[mt][nt] = __builtin_amdgcn_mfma_f32_32x32x16_bf16(bfr[nt], af[mt], acc[mt][nt], 0, 0, 0);
    }
  }
  // token = arow0 + wm*128 + mt*32 + m_lane; channel = brow0 + wn*64 + nt*32 + g*8 + q4*4 + j
#pragma unroll
  for (int mt = 0; mt < 4; mt++) {
    long row = arow0 + wm * 128 + mt * 32 + m_lane;
#pragma unroll
    for (int nt = 0; nt < 2; nt++) {
#pragma unroll
      for (int g = 0; g < 4; g++) {
        long col = brow0 + wn * 64 + nt * 32 + g * 8 + q4 * 4;
        bf16 tmp[4];
#pragma unroll
        for (int j = 0; j < 4; j++) tmp[j] = __float2bfloat16(acc[mt][nt][g * 4 + j]);
        *(uint2*)(C + row * N1 + col) = *(uint2*)tmp;
      }
    }
  }
}

// ---------------- GEMM2: 128x128 block, BK=64, 16x16x32 MFMA, fused residual ----------------
// Swapped operands -> lane holds 4 consecutive channels -> float4 residual epilogue.
template <int EPI>
__global__ __launch_bounds__(256) void gemm_bt(
    const bf16* __restrict__ A, const bf16* __restrict__ Bt,
    void* __restrict__ Cout, const float* __restrict__ resid,
    int M, int N, int K) {
  __shared__ __align__(16) bf16 As[128 * 64];  // 16 KB
  __shared__ __align__(16) bf16 Bs[128 * 64];  // 16 KB
  int tid = threadIdx.x;
  int lane = tid & 63, wave = tid >> 6;
  int wm = wave & 1, wn = wave >> 1;  // 2x2 wave grid, 64x64 each
  long arow0 = (long)blockIdx.y * 128;
  long brow0 = (long)blockIdx.x * 128;
  int r = lane & 15, q = lane >> 4;
  f32x4 acc[4][4] = {};

  for (int k0 = 0; k0 < K; k0 += 64) {
    __syncthreads();
#pragma unroll
    for (int i = 0; i < 4; i++) {  // 1024 chunks each for A and B
      int c = (wave * 4 + i) * 64 + lane;
      int row, kc; swz64_dec(c, row, kc);
      async_copy16(A + (arow0 + row) * K + k0 + kc * 8, (char*)As + (wave * 4 + i) * 1024);
      async_copy16(Bt + (brow0 + row) * K + k0 + kc * 8, (char*)Bs + (wave * 4 + i) * 1024);
    }
    __syncthreads();
    const bf16x8* AsV = (const bf16x8*)As;
    const bf16x8* BsV = (const bf16x8*)Bs;
#pragma unroll
    for (int ks = 0; ks < 2; ks++) {  // two 32-element k-slices
      bf16x8 af[4], bfr[4];
#pragma unroll
      for (int mt = 0; mt < 4; mt++) af[mt] = AsV[swz64(wm * 64 + mt * 16 + r, ks * 4 + q)];
#pragma unroll
      for (int nt = 0; nt < 4; nt++) bfr[nt] = BsV[swz64(wn * 64 + nt * 16 + r, ks * 4 + q)];
#pragma unroll
      for (int mt = 0; mt < 4; mt++)
#pragma unroll
        for (int nt = 0; nt < 4; nt++)
          acc[mt][nt] = __builtin_amdgcn_mfma_f32_16x16x32_bf16(bfr[nt], af[mt], acc[mt][nt], 0, 0, 0);
    }
  }

  // Swapped C/D mapping: token = lane&15 (mt tile), channel = q*4+reg (nt tile).
  if (EPI == 0) {
    bf16* C = (bf16*)Cout;
#pragma unroll
    for (int mt = 0; mt < 4; mt++) {
      long row = arow0 + wm * 64 + mt * 16 + r;  // token
#pragma unroll
      for (int nt = 0; nt < 4; nt++) {
        long col = brow0 + wn * 64 + nt * 16 + q * 4;  // channel base
        bf16 tmp[4];
#pragma unroll
        for (int reg = 0; reg < 4; reg++) tmp[reg] = __float2bfloat16(acc[mt][nt][reg]);
        *(uint2*)(C + row * N + col) = *(uint2*)tmp;
      }
    }
  } else {
    float* C = (float*)Cout;
#pragma unroll
    for (int mt = 0; mt < 4; mt++) {
      long row = arow0 + wm * 64 + mt * 16 + r;  // token
#pragma unroll
      for (int nt = 0; nt < 4; nt++) {
        long col = brow0 + wn * 64 + nt * 16 + q * 4;  // channel base
        float4 rv = *(const float4*)(resid + row * N + col);
        float4 ov;
        ov.x = acc[mt][nt][0] + rv.x;
        ov.y = acc[mt][nt][1] + rv.y;
        ov.z = acc[mt][nt][2] + rv.z;
        ov.w = acc[mt][nt][3] + rv.w;
        *(float4*)(C + row * N + col) = ov;
      }
    }
  }
}

// ---------------- chunked gated linear scan ----------------
// h_t = a_t*h_{t-1} + u_t, a_t = sigmoid(Kraw_{t-1}) (a_0=1),
// u_t = uraw_t*sigmoid(gin_t)*(1-sigmoid(Kraw_t)). Chunk composes to h_out = A*h_in + U.

// Pass A: per (batch, channel, chunk) thread reduces the chunk to (A, U).
__global__ __launch_bounds__(256) void chunk_summary_kernel(
    const bf16* __restrict__ C1, float* __restrict__ carryA,
    float* __restrict__ carryU) {
  int b = blockIdx.x;
  int ch = blockIdx.y * 256 + threadIdx.x;
  int chunk = blockIdx.z;
  int t0 = chunk * CHUNKL;
  long base = ((long)b * SEQ) * N1 + ch;
  float kp = 0.0f;
  if (chunk != 0) kp = __bfloat162float(C1[base + (long)(t0 - 1) * N1]);
  float a_first = (chunk == 0) ? 1.0f : sigmoidf_(kp);
  float A = 1.0f, U = 0.0f;
#pragma unroll 8
  for (int t = t0; t < t0 + CHUNKL; t++) {
    long off = base + (long)t * N1;
    float kraw = __bfloat162float(C1[off]);
    float uraw = __bfloat162float(C1[off + 2048]);
    float gin  = __bfloat162float(C1[off + 4096]);
    float a = (t == t0) ? a_first : sigmoidf_(kp);
    float sK = sigmoidf_(kraw);
    float u = uraw * sigmoidf_(gin) * (1.0f - sK);
    A *= a;
    U = a * U + u;
    kp = kraw;
  }
  int cidx = (b * NCHUNK + chunk) * STATE + ch;
  carryA[cidx] = A;
  carryU[cidx] = U;
}

// Pass B: exclusive scan of chunk carries along the chunk axis per channel.
__global__ __launch_bounds__(256) void carry_scan_kernel(
    const float* __restrict__ carryA, const float* __restrict__ carryU,
    float* __restrict__ carryIn) {
  int idx = blockIdx.x * 256 + threadIdx.x;  // b*STATE + ch
  int b = idx >> 11;
  int ch = idx & 2047;
  float h = 0.0f;
#pragma unroll
  for (int c = 0; c < NCHUNK; c++) {
    int cidx = (b * NCHUNK + c) * STATE + ch;
    carryIn[cidx] = h;
    h = carryA[cidx] * h + carryU[cidx];
  }
}

// Pass C: per-chunk local scan seeded with carryIn; writes h*sigmoid(g_out).
__global__ __launch_bounds__(256) void scan_chunk_kernel(
    const bf16* __restrict__ C1, const float* __restrict__ carryIn,
    bf16* __restrict__ out) {
  int b = blockIdx.x;              // batch 0..3
  int c0 = blockIdx.y * 32;        // channel base
  int chunk = blockIdx.z;
  int tstart = chunk * CHUNKL;
  __shared__ float a_s[32][65], u_s[32][65], h_s[32][65];
  int tid = threadIdx.x;
  int lane = tid & 63, wave = tid >> 6;
  int cc = tid & 31;   // channel within tile (load/store phases)
  int tq = tid >> 5;   // 0..7

  float carryH[8], carryK[8];
#pragma unroll
  for (int i = 0; i < 8; i++) {
    int ch = c0 + wave * 8 + i;
    carryH[i] = carryIn[(b * NCHUNK + chunk) * STATE + ch];
    carryK[i] = (chunk == 0)
                    ? 1.0f
                    : sigmoidf_(__bfloat162float(
                          C1[((long)(b * SEQ + tstart - 1)) * N1 + ch]));
  }

  float g_r[8];
  for (int t0 = tstart; t0 < tstart + CHUNKL; t0 += 64) {
#pragma unroll
    for (int i = 0; i < 8; i++) {
      int t = tq * 8 + i;
      long rowoff = ((long)(b * SEQ + t0 + t)) * N1 + c0 + cc;
      float kraw = __bfloat162float(C1[rowoff]);
      float uraw = __bfloat162float(C1[rowoff + 2048]);
      float gin  = __bfloat162float(C1[rowoff + 4096]);
      float gout = __bfloat162float(C1[rowoff + 6144]);
      float aK = sigmoidf_(kraw);
      a_s[cc][t] = aK;
      u_s[cc][t] = uraw * sigmoidf_(gin) * (1.0f - aK);
      g_r[i] = sigmoidf_(gout);
    }
    __syncthreads();
#pragma unroll
    for (int i = 0; i < 8; i++) {
      int ch = wave * 8 + i;
      float aK = a_s[ch][lane];
      float u = u_s[ch][lane];
      float a = __shfl_up(aK, 1);     // a_t = K_{t-1}
      if (lane == 0) a = carryK[i];
      float A = a, U = u;
#pragma unroll
      for (int d = 1; d < 64; d <<= 1) {
        float Au = __shfl_up(A, d);
        float Uu = __shfl_up(U, d);
        if (lane >= d) { U += A * Uu; A *= Au; }
      }
      float h = U + A * carryH[i];
      carryH[i] = __shfl(h, 63);
      carryK[i] = __shfl(aK, 63);
      h_s[ch][lane] = h;
    }
    __syncthreads();
#pragma unroll
    for (int i = 0; i < 8; i++) {
      int t = tq * 8 + i;
      out[((long)(b * SEQ + t0 + t)) * STATE + c0 + cc] =
          __float2bfloat16(h_s[cc][t] * g_r[i]);
    }
    __syncthreads();
  }
}

extern "C" void kernel_launch(void* const* d_in, const int* in_sizes, int n_in,
                              void* d_out, int out_size, void* d_ws, size_t ws_size,
                              hipStream_t stream) {
  const float* x    = (const float*)d_in[0];
  const float* ls   = (const float*)d_in[1];
  const float* rs   = (const float*)d_in[2];
  const float* ss   = (const float*)d_in[3];
  const float* Wk   = (const float*)d_in[4];
  const float* Wugg = (const float*)d_in[5];
  const float* Wout = (const float*)d_in[6];
  float* out = (float*)d_out;

  // workspace layout (~205.5 MB total)
  char* ws = (char*)d_ws;
  bf16* W1t = (bf16*)ws;                                   // [8192][1024] = Wk^T | Wugg^T
  bf16* W2t = (bf16*)(ws + 16777216);                      // [1024][2048] = Wout^T
  bf16* xn  = (bf16*)(ws + 16777216 + 4194304);            // [8192][1024]
  bf16* C1  = (bf16*)(ws + 16777216 + 4194304 + 16777216); // [8192][8192]
  bf16* sco = (bf16*)(ws + 16777216 + 4194304 + 16777216 + 134217728); // [8192][2048]
  // carry buffers (3 x 512 KB) overlay the xn region: xn is dead after GEMM1.
  float* carryA  = (float*)xn;
  float* carryU  = carryA + BATCH * NCHUNK * STATE;
  float* carryIn = carryU + BATCH * NCHUNK * STATE;

  // weights -> bf16, transposed to [N][K]
  transpose_bf16_kernel<<<dim3(STATE / 32, DIMS / 32), 256, 0, stream>>>(Wk, W1t, DIMS, STATE);
  transpose_bf16_kernel<<<dim3(3 * STATE / 32, DIMS / 32), 256, 0, stream>>>(
      Wugg, W1t + (long)STATE * DIMS, DIMS, 3 * STATE);
  transpose_bf16_kernel<<<dim3(DIMS / 32, STATE / 32), 256, 0, stream>>>(Wout, W2t, STATE, DIMS);

  rmsnorm_kernel<<<TOKENS, 256, 0, stream>>>(x, ls, rs, ss, xn);

  gemm1_big<<<dim3(N1 / 128, TOKENS / 256), 256, 0, stream>>>(xn, W1t, C1);

  chunk_summary_kernel<<<dim3(BATCH, STATE / 256, NCHUNK), 256, 0, stream>>>(
      C1, carryA, carryU);
  carry_scan_kernel<<<dim3(BATCH * STATE / 256), 256, 0, stream>>>(
      carryA, carryU, carryIn);
  scan_chunk_kernel<<<dim3(BATCH, STATE / 32, NCHUNK), 256, 0, stream>>>(
      C1, carryIn, sco);

  gemm_bt<1><<<dim3(DIMS / 128, TOKENS / 128), 256, 0, stream>>>(
      sco, W2t, (void*)out, x, TOKENS, DIMS, STATE);
}

// Round 7
// 444.756 us; speedup vs baseline: 1.0750x; 1.0020x over previous
//
#include <hip/hip_runtime.h>
#include <hip/hip_bf16.h>
#include <stdint.h>

#define DIMS 1024
#define STATE 2048
#define BATCH 4
#define SEQ 2048
#define TOKENS 8192   // BATCH*SEQ
#define N1 8192       // STATE + 3*STATE columns of fused GEMM1
#define NCHUNK 16
#define CHUNKL (SEQ / NCHUNK)   // 128

typedef __hip_bfloat16 bf16;
typedef __attribute__((ext_vector_type(8))) short bf16x8;
typedef __attribute__((ext_vector_type(4))) float f32x4;
typedef __attribute__((ext_vector_type(16))) float f32x16;

__device__ __forceinline__ float sigmoidf_(float x) {
  return 1.0f / (1.0f + __expf(-x));
}

// async global->LDS, 16B per lane. LDS dest must be wave-uniform base; HW does base + lane*16.
__device__ __forceinline__ void async_copy16(const void* g, void* l) {
  __builtin_amdgcn_global_load_lds(
      (const __attribute__((address_space(1))) void*)(uintptr_t)g,
      (__attribute__((address_space(3))) void*)(uint32_t)(uintptr_t)l,
      16, 0, 0);
}

// ---- LDS XOR swizzles ----
// 32-bf16 (64 B) rows: bank period = row pair.
__device__ __forceinline__ int swz32(int row, int kc) {
  int line = row >> 1;
  int sub = ((row & 1) << 2) | kc;
  return (line << 3) | (sub ^ (line & 7));
}
__device__ __forceinline__ void swz32_dec(int c, int& row, int& kc) {
  int line = c >> 3;
  int sub = (c & 7) ^ (line & 7);
  row = (line << 1) | (sub >> 2);
  kc = sub & 3;
}
// 64-bf16 (128 B) rows: one row == one bank period.
__device__ __forceinline__ int swz64(int row, int kc) {
  return (row << 3) | (kc ^ (row & 7));
}
__device__ __forceinline__ void swz64_dec(int c, int& row, int& kc) {
  row = c >> 3;
  kc = (c & 7) ^ (row & 7);
}

// ---------------- weight transpose + fp32->bf16 cast: W[K][N] -> Wt[N][K] ----------------
__global__ __launch_bounds__(256) void transpose_bf16_kernel(
    const float* __restrict__ W, bf16* __restrict__ Wt, int K, int N) {
  __shared__ float tile[32][33];
  int tx = threadIdx.x & 31;
  int ty = threadIdx.x >> 5;  // 0..7
  long col = (long)blockIdx.x * 32 + tx;
  long rowb = (long)blockIdx.y * 32;
#pragma unroll
  for (int i = 0; i < 32; i += 8)
    tile[ty + i][tx] = W[(rowb + ty + i) * N + col];
  __syncthreads();
  long ocol = rowb + tx;                      // k index
  long orow = (long)blockIdx.x * 32 + ty;     // n index
#pragma unroll
  for (int i = 0; i < 32; i += 8)
    Wt[(orow + i) * K + ocol] = __float2bfloat16(tile[tx][ty + i]);
}

// ---------------- split RMSNorm -> bf16 ----------------
__global__ __launch_bounds__(256) void rmsnorm_kernel(
    const float* __restrict__ x, const float* __restrict__ ls,
    const float* __restrict__ rs, const float* __restrict__ ss,
    bf16* __restrict__ xn) {
  int token = blockIdx.x;
  int tid = threadIdx.x;  // 256 threads, 4 floats each
  const float4* xt = (const float4*)(x + (long)token * DIMS);
  float4 v = xt[tid];
  float s = v.x * v.x + v.y * v.y + v.z * v.z + v.w * v.w;
#pragma unroll
  for (int d = 32; d > 0; d >>= 1) s += __shfl_down(s, d);
  __shared__ float parts[4];
  if ((tid & 63) == 0) parts[tid >> 6] = s;
  __syncthreads();
  int j = tid * 4;
  bool left = j < 512;  // waves 0,1 cover elements 0..511
  float sum = left ? (parts[0] + parts[1]) : (parts[2] + parts[3]);
  float n = sqrtf(sum * (1.0f / 512.0f));  // ||v||*d^-1/2
  float inv = 1.0f / (n + 1e-8f);
  const float4* sc = (const float4*)(left ? ls : rs);
  float4 g = sc[left ? tid : tid - 128];
  float4 p = ((const float4*)ss)[tid];
  bf16* o = xn + (long)token * DIMS + j;
  o[0] = __float2bfloat16(v.x * g.x * inv * p.x);
  o[1] = __float2bfloat16(v.y * g.y * inv * p.y);
  o[2] = __float2bfloat16(v.z * g.z * inv * p.z);
  o[3] = __float2bfloat16(v.w * g.w * inv * p.w);
}

// ---------------- GEMM1: 256x128 block, BK=32, DOUBLE-BUFFERED ----------------
// 4 waves x (128x64) via 32x32x16 MFMA, swapped operands (D col=token, row=channel).
// K-loop unrolled x2 over two static LDS buffer sets so the vmcnt(0) drain at the
// barrier waits on loads issued one full compute phase earlier (latency hidden).
__device__ __forceinline__ void g1_stage(const bf16* __restrict__ A,
                                         const bf16* __restrict__ Bt,
                                         long arow0, long brow0, int k0,
                                         int wave, int lane, bf16* As, bf16* Bs) {
  const int K = DIMS;
#pragma unroll
  for (int i = 0; i < 4; i++) {  // A: 1024 16B chunks (256 rows x 32)
    int c = (wave * 4 + i) * 64 + lane;
    int row, kc; swz32_dec(c, row, kc);
    async_copy16(A + (arow0 + row) * K + k0 + kc * 8, (char*)As + (wave * 4 + i) * 1024);
  }
#pragma unroll
  for (int i = 0; i < 2; i++) {  // B: 512 chunks (128 rows x 32)
    int c = (wave * 2 + i) * 64 + lane;
    int row, kc; swz32_dec(c, row, kc);
    async_copy16(Bt + (brow0 + row) * K + k0 + kc * 8, (char*)Bs + (wave * 2 + i) * 1024);
  }
}

__global__ __launch_bounds__(256, 2) void gemm1_big(
    const bf16* __restrict__ A, const bf16* __restrict__ Bt, bf16* __restrict__ C) {
  __shared__ __align__(16) bf16 As0[256 * 32], As1[256 * 32];  // 16 KB each
  __shared__ __align__(16) bf16 Bs0[128 * 32], Bs1[128 * 32];  // 8 KB each
  int tid = threadIdx.x;
  int lane = tid & 63, wave = tid >> 6;
  int wm = wave & 1, wn = wave >> 1;
  long arow0 = (long)blockIdx.y * 256;
  long brow0 = (long)blockIdx.x * 128;
  int m_lane = lane & 31, q4 = lane >> 5;
  f32x16 acc[4][2] = {};

  g1_stage(A, Bt, arow0, brow0, 0, wave, lane, As0, Bs0);
  __syncthreads();  // drain: buf0 ready (cold stall, once)

  for (int it = 0; it < 32; it += 2) {
    // ---- body A: compute buf0, prefetch buf1 ----
    {
      const bf16x8* AsV = (const bf16x8*)As0;
      const bf16x8* BsV = (const bf16x8*)Bs0;
      bf16x8 af[2][4], bfr[2][2];
#pragma unroll
      for (int ks = 0; ks < 2; ks++) {
        int kc = ks * 2 + q4;
#pragma unroll
        for (int mt = 0; mt < 4; mt++) af[ks][mt] = AsV[swz32(wm * 128 + mt * 32 + m_lane, kc)];
#pragma unroll
        for (int nt = 0; nt < 2; nt++) bfr[ks][nt] = BsV[swz32(wn * 64 + nt * 32 + m_lane, kc)];
      }
      g1_stage(A, Bt, arow0, brow0, (it + 1) * 32, wave, lane, As1, Bs1);  // always < K
#pragma unroll
      for (int ks = 0; ks < 2; ks++)
#pragma unroll
        for (int mt = 0; mt < 4; mt++)
#pragma unroll
          for (int nt = 0; nt < 2; nt++)
            acc[mt][nt] = __builtin_amdgcn_mfma_f32_32x32x16_bf16(bfr[ks][nt], af[ks][mt], acc[mt][nt], 0, 0, 0);
      __syncthreads();  // drains prefetch (issued ~1 compute phase ago) + read-done
    }
    // ---- body B: compute buf1, prefetch buf0 ----
    {
      const bf16x8* AsV = (const bf16x8*)As1;
      const bf16x8* BsV = (const bf16x8*)Bs1;
      bf16x8 af[2][4], bfr[2][2];
#pragma unroll
      for (int ks = 0; ks < 2; ks++) {
        int kc = ks * 2 + q4;
#pragma unroll
        for (int mt = 0; mt < 4; mt++) af[ks][mt] = AsV[swz32(wm * 128 + mt * 32 + m_lane, kc)];
#pragma unroll
        for (int nt = 0; nt < 2; nt++) bfr[ks][nt] = BsV[swz32(wn * 64 + nt * 32 + m_lane, kc)];
      }
      if (it + 2 < 32)
        g1_stage(A, Bt, arow0, brow0, (it + 2) * 32, wave, lane, As0, Bs0);
#pragma unroll
      for (int ks = 0; ks < 2; ks++)
#pragma unroll
        for (int mt = 0; mt < 4; mt++)
#pragma unroll
          for (int nt = 0; nt < 2; nt++)
            acc[mt][nt] = __builtin_amdgcn_mfma_f32_32x32x16_bf16(bfr[ks][nt], af[ks][mt], acc[mt][nt], 0, 0, 0);
      __syncthreads();
    }
  }
  // token = arow0 + wm*128 + mt*32 + m_lane; channel = brow0 + wn*64 + nt*32 + g*8 + q4*4 + j
#pragma unroll
  for (int mt = 0; mt < 4; mt++) {
    long row = arow0 + wm * 128 + mt * 32 + m_lane;
#pragma unroll
    for (int nt = 0; nt < 2; nt++) {
#pragma unroll
      for (int g = 0; g < 4; g++) {
        long col = brow0 + wn * 64 + nt * 32 + g * 8 + q4 * 4;
        bf16 tmp[4];
#pragma unroll
        for (int j = 0; j < 4; j++) tmp[j] = __float2bfloat16(acc[mt][nt][g * 4 + j]);
        *(uint2*)(C + row * N1 + col) = *(uint2*)tmp;
      }
    }
  }
}

// ---------------- GEMM2: 128x128 block, BK=64, DOUBLE-BUFFERED, fused residual ----------------
__device__ __forceinline__ void g2_stage(const bf16* __restrict__ A,
                                         const bf16* __restrict__ Bt,
                                         long arow0, long brow0, int k0, int K,
                                         int wave, int lane, bf16* As, bf16* Bs) {
#pragma unroll
  for (int i = 0; i < 4; i++) {  // 1024 chunks each (128 rows x 64)
    int c = (wave * 4 + i) * 64 + lane;
    int row, kc; swz64_dec(c, row, kc);
    async_copy16(A + (arow0 + row) * K + k0 + kc * 8, (char*)As + (wave * 4 + i) * 1024);
    async_copy16(Bt + (brow0 + row) * K + k0 + kc * 8, (char*)Bs + (wave * 4 + i) * 1024);
  }
}

__global__ __launch_bounds__(256) void gemm2_resid(
    const bf16* __restrict__ A, const bf16* __restrict__ Bt,
    float* __restrict__ C, const float* __restrict__ resid) {
  __shared__ __align__(16) bf16 As0[128 * 64], As1[128 * 64];  // 16 KB each
  __shared__ __align__(16) bf16 Bs0[128 * 64], Bs1[128 * 64];
  const int K = STATE, N = DIMS;
  int tid = threadIdx.x;
  int lane = tid & 63, wave = tid >> 6;
  int wm = wave & 1, wn = wave >> 1;
  long arow0 = (long)blockIdx.y * 128;
  long brow0 = (long)blockIdx.x * 128;
  int r = lane & 15, q = lane >> 4;
  f32x4 acc[4][4] = {};

  g2_stage(A, Bt, arow0, brow0, 0, K, wave, lane, As0, Bs0);
  __syncthreads();

  for (int it = 0; it < 32; it += 2) {
    {
      const bf16x8* AsV = (const bf16x8*)As0;
      const bf16x8* BsV = (const bf16x8*)Bs0;
      bf16x8 af[2][4], bfr[2][4];
#pragma unroll
      for (int ks = 0; ks < 2; ks++) {
#pragma unroll
        for (int mt = 0; mt < 4; mt++) af[ks][mt] = AsV[swz64(wm * 64 + mt * 16 + r, ks * 4 + q)];
#pragma unroll
        for (int nt = 0; nt < 4; nt++) bfr[ks][nt] = BsV[swz64(wn * 64 + nt * 16 + r, ks * 4 + q)];
      }
      g2_stage(A, Bt, arow0, brow0, (it + 1) * 64, K, wave, lane, As1, Bs1);
#pragma unroll
      for (int ks = 0; ks < 2; ks++)
#pragma unroll
        for (int mt = 0; mt < 4; mt++)
#pragma unroll
          for (int nt = 0; nt < 4; nt++)
            acc[mt][nt] = __builtin_amdgcn_mfma_f32_16x16x32_bf16(bfr[ks][nt], af[ks][mt], acc[mt][nt], 0, 0, 0);
      __syncthreads();
    }
    {
      const bf16x8* AsV = (const bf16x8*)As1;
      const bf16x8* BsV = (const bf16x8*)Bs1;
      bf16x8 af[2][4], bfr[2][4];
#pragma unroll
      for (int ks = 0; ks < 2; ks++) {
#pragma unroll
        for (int mt = 0; mt < 4; mt++) af[ks][mt] = AsV[swz64(wm * 64 + mt * 16 + r, ks * 4 + q)];
#pragma unroll
        for (int nt = 0; nt < 4; nt++) bfr[ks][nt] = BsV[swz64(wn * 64 + nt * 16 + r, ks * 4 + q)];
      }
      if (it + 2 < 32)
        g2_stage(A, Bt, arow0, brow0, (it + 2) * 64, K, wave, lane, As0, Bs0);
#pragma unroll
      for (int ks = 0; ks < 2; ks++)
#pragma unroll
        for (int mt = 0; mt < 4; mt++)
#pragma unroll
          for (int nt = 0; nt < 4; nt++)
            acc[mt][nt] = __builtin_amdgcn_mfma_f32_16x16x32_bf16(bfr[ks][nt], af[ks][mt], acc[mt][nt], 0, 0, 0);
      __syncthreads();
    }
  }

  // token = lane&15 (mt tile), channel = q*4+reg (nt tile) -> float4 epilogue.
#pragma unroll
  for (int mt = 0; mt < 4; mt++) {
    long row = arow0 + wm * 64 + mt * 16 + r;  // token
#pragma unroll
    for (int nt = 0; nt < 4; nt++) {
      long col = brow0 + wn * 64 + nt * 16 + q * 4;  // channel base
      float4 rv = *(const float4*)(resid + row * N + col);
      float4 ov;
      ov.x = acc[mt][nt][0] + rv.x;
      ov.y = acc[mt][nt][1] + rv.y;
      ov.z = acc[mt][nt][2] + rv.z;
      ov.w = acc[mt][nt][3] + rv.w;
      *(float4*)(C + row * N + col) = ov;
    }
  }
}

// ---------------- chunked gated linear scan ----------------
// h_t = a_t*h_{t-1} + u_t, a_t = sigmoid(Kraw_{t-1}) (a_0=1),
// u_t = uraw_t*sigmoid(gin_t)*(1-sigmoid(Kraw_t)). Chunk composes to h_out = A*h_in + U.

// Pass A: per (batch, channel, chunk) thread reduces the chunk to (A, U).
__global__ __launch_bounds__(256) void chunk_summary_kernel(
    const bf16* __restrict__ C1, float* __restrict__ carryA,
    float* __restrict__ carryU) {
  int b = blockIdx.x;
  int ch = blockIdx.y * 256 + threadIdx.x;
  int chunk = blockIdx.z;
  int t0 = chunk * CHUNKL;
  long base = ((long)b * SEQ) * N1 + ch;
  float kp = 0.0f;
  if (chunk != 0) kp = __bfloat162float(C1[base + (long)(t0 - 1) * N1]);
  float a_first = (chunk == 0) ? 1.0f : sigmoidf_(kp);
  float A = 1.0f, U = 0.0f;
#pragma unroll 8
  for (int t = t0; t < t0 + CHUNKL; t++) {
    long off = base + (long)t * N1;
    float kraw = __bfloat162float(C1[off]);
    float uraw = __bfloat162float(C1[off + 2048]);
    float gin  = __bfloat162float(C1[off + 4096]);
    float a = (t == t0) ? a_first : sigmoidf_(kp);
    float sK = sigmoidf_(kraw);
    float u = uraw * sigmoidf_(gin) * (1.0f - sK);
    A *= a;
    U = a * U + u;
    kp = kraw;
  }
  int cidx = (b * NCHUNK + chunk) * STATE + ch;
  carryA[cidx] = A;
  carryU[cidx] = U;
}

// Pass B: exclusive scan of chunk carries along the chunk axis per channel.
__global__ __launch_bounds__(256) void carry_scan_kernel(
    const float* __restrict__ carryA, const float* __restrict__ carryU,
    float* __restrict__ carryIn) {
  int idx = blockIdx.x * 256 + threadIdx.x;  // b*STATE + ch
  int b = idx >> 11;
  int ch = idx & 2047;
  float h = 0.0f;
#pragma unroll
  for (int c = 0; c < NCHUNK; c++) {
    int cidx = (b * NCHUNK + c) * STATE + ch;
    carryIn[cidx] = h;
    h = carryA[cidx] * h + carryU[cidx];
  }
}

// Pass C: per-chunk local scan seeded with carryIn; writes h*sigmoid(g_out).
__global__ __launch_bounds__(256) void scan_chunk_kernel(
    const bf16* __restrict__ C1, const float* __restrict__ carryIn,
    bf16* __restrict__ out) {
  int b = blockIdx.x;              // batch 0..3
  int c0 = blockIdx.y * 32;        // channel base
  int chunk = blockIdx.z;
  int tstart = chunk * CHUNKL;
  __shared__ float a_s[32][65], u_s[32][65], h_s[32][65];
  int tid = threadIdx.x;
  int lane = tid & 63, wave = tid >> 6;
  int cc = tid & 31;   // channel within tile (load/store phases)
  int tq = tid >> 5;   // 0..7

  float carryH[8], carryK[8];
#pragma unroll
  for (int i = 0; i < 8; i++) {
    int ch = c0 + wave * 8 + i;
    carryH[i] = carryIn[(b * NCHUNK + chunk) * STATE + ch];
    carryK[i] = (chunk == 0)
                    ? 1.0f
                    : sigmoidf_(__bfloat162float(
                          C1[((long)(b * SEQ + tstart - 1)) * N1 + ch]));
  }

  float g_r[8];
  for (int t0 = tstart; t0 < tstart + CHUNKL; t0 += 64) {
#pragma unroll
    for (int i = 0; i < 8; i++) {
      int t = tq * 8 + i;
      long rowoff = ((long)(b * SEQ + t0 + t)) * N1 + c0 + cc;
      float kraw = __bfloat162float(C1[rowoff]);
      float uraw = __bfloat162float(C1[rowoff + 2048]);
      float gin  = __bfloat162float(C1[rowoff + 4096]);
      float gout = __bfloat162float(C1[rowoff + 6144]);
      float aK = sigmoidf_(kraw);
      a_s[cc][t] = aK;
      u_s[cc][t] = uraw * sigmoidf_(gin) * (1.0f - aK);
      g_r[i] = sigmoidf_(gout);
    }
    __syncthreads();
#pragma unroll
    for (int i = 0; i < 8; i++) {
      int ch = wave * 8 + i;
      float aK = a_s[ch][lane];
      float u = u_s[ch][lane];
      float a = __shfl_up(aK, 1);     // a_t = K_{t-1}
      if (lane == 0) a = carryK[i];
      float A = a, U = u;
#pragma unroll
      for (int d = 1; d < 64; d <<= 1) {
        float Au = __shfl_up(A, d);
        float Uu = __shfl_up(U, d);
        if (lane >= d) { U += A * Uu; A *= Au; }
      }
      float h = U + A * carryH[i];
      carryH[i] = __shfl(h, 63);
      carryK[i] = __shfl(aK, 63);
      h_s[ch][lane] = h;
    }
    __syncthreads();
#pragma unroll
    for (int i = 0; i < 8; i++) {
      int t = tq * 8 + i;
      out[((long)(b * SEQ + t0 + t)) * STATE + c0 + cc] =
          __float2bfloat16(h_s[cc][t] * g_r[i]);
    }
    __syncthreads();
  }
}

extern "C" void kernel_launch(void* const* d_in, const int* in_sizes, int n_in,
                              void* d_out, int out_size, void* d_ws, size_t ws_size,
                              hipStream_t stream) {
  const float* x    = (const float*)d_in[0];
  const float* ls   = (const float*)d_in[1];
  const float* rs   = (const float*)d_in[2];
  const float* ss   = (const float*)d_in[3];
  const float* Wk   = (const float*)d_in[4];
  const float* Wugg = (const float*)d_in[5];
  const float* Wout = (const float*)d_in[6];
  float* out = (float*)d_out;

  // workspace layout (~205.5 MB total)
  char* ws = (char*)d_ws;
  bf16* W1t = (bf16*)ws;                                   // [8192][1024] = Wk^T | Wugg^T
  bf16* W2t = (bf16*)(ws + 16777216);                      // [1024][2048] = Wout^T
  bf16* xn  = (bf16*)(ws + 16777216 + 4194304);            // [8192][1024]
  bf16* C1  = (bf16*)(ws + 16777216 + 4194304 + 16777216); // [8192][8192]
  bf16* sco = (bf16*)(ws + 16777216 + 4194304 + 16777216 + 134217728); // [8192][2048]
  // carry buffers (3 x 512 KB) overlay the xn region: xn is dead after GEMM1.
  float* carryA  = (float*)xn;
  float* carryU  = carryA + BATCH * NCHUNK * STATE;
  float* carryIn = carryU + BATCH * NCHUNK * STATE;

  // weights -> bf16, transposed to [N][K]
  transpose_bf16_kernel<<<dim3(STATE / 32, DIMS / 32), 256, 0, stream>>>(Wk, W1t, DIMS, STATE);
  transpose_bf16_kernel<<<dim3(3 * STATE / 32, DIMS / 32), 256, 0, stream>>>(
      Wugg, W1t + (long)STATE * DIMS, DIMS, 3 * STATE);
  transpose_bf16_kernel<<<dim3(DIMS / 32, STATE / 32), 256, 0, stream>>>(Wout, W2t, STATE, DIMS);

  rmsnorm_kernel<<<TOKENS, 256, 0, stream>>>(x, ls, rs, ss, xn);

  gemm1_big<<<dim3(N1 / 128, TOKENS / 256), 256, 0, stream>>>(xn, W1t, C1);

  chunk_summary_kernel<<<dim3(BATCH, STATE / 256, NCHUNK), 256, 0, stream>>>(
      C1, carryA, carryU);
  carry_scan_kernel<<<dim3(BATCH * STATE / 256), 256, 0, stream>>>(
      carryA, carryU, carryIn);
  scan_chunk_kernel<<<dim3(BATCH, STATE / 32, NCHUNK), 256, 0, stream>>>(
      C1, carryIn, sco);

  gemm2_resid<<<dim3(DIMS / 128, TOKENS / 128), 256, 0, stream>>>(
      sco, W2t, out, x);
}

// Round 8
// 404.826 us; speedup vs baseline: 1.1811x; 1.0986x over previous
//
#include <hip/hip_runtime.h>
#include <hip/hip_bf16.h>
#include <hip/hip_fp8.h>
#include <stdint.h>

#define DIMS 1024
#define STATE 2048
#define BATCH 4
#define SEQ 2048
#define TOKENS 8192   // BATCH*SEQ
#define N1 8192       // STATE + 3*STATE columns of fused GEMM1
#define NCHUNK 16
#define CHUNKL (SEQ / NCHUNK)   // 128

typedef __hip_bfloat16 bf16;
typedef unsigned char u8;
typedef __attribute__((ext_vector_type(8))) short bf16x8;
typedef __attribute__((ext_vector_type(4))) float f32x4;
typedef __attribute__((ext_vector_type(16))) float f32x16;
typedef __attribute__((ext_vector_type(2))) long v2i64;

// static fp8 scales: xn*32, W1*256 -> acc/8192 in epilogue
#define XN_SCALE 32.0f
#define W1_SCALE 256.0f
#define INV_SCALE (1.0f / 8192.0f)

__device__ __forceinline__ float sigmoidf_(float x) {
  return 1.0f / (1.0f + __expf(-x));
}

__device__ __forceinline__ u8 to_fp8(float f) {
  __hip_fp8_e4m3 h(f);
  return h.__x;
}

// k-permutation baked into fp8 producers: swap bits 3<->4 of the k index so a
// lane's MFMA operands for two consecutive 16-k slices (k = s*16 + q4*8 + [0,8))
// are 16 CONTIGUOUS bytes -> one ds_read_b128 feeds two mfma_..._fp8 issues.
__device__ __forceinline__ int kperm(int k) {
  return (k & ~24) | ((k & 8) << 1) | ((k & 16) >> 1);
}

// async global->LDS, 16B per lane. LDS dest must be wave-uniform base; HW does base + lane*16.
__device__ __forceinline__ void async_copy16(const void* g, void* l) {
  __builtin_amdgcn_global_load_lds(
      (const __attribute__((address_space(1))) void*)(uintptr_t)g,
      (__attribute__((address_space(3))) void*)(uint32_t)(uintptr_t)l,
      16, 0, 0);
}

// ---- LDS XOR swizzles ----
// 64 B rows (4 x 16B chunks): bank period = row pair.
__device__ __forceinline__ int swz32(int row, int kc) {
  int line = row >> 1;
  int sub = ((row & 1) << 2) | kc;
  return (line << 3) | (sub ^ (line & 7));
}
__device__ __forceinline__ void swz32_dec(int c, int& row, int& kc) {
  int line = c >> 3;
  int sub = (c & 7) ^ (line & 7);
  row = (line << 1) | (sub >> 2);
  kc = sub & 3;
}
// 128 B rows (8 x 16B chunks): one row == one bank period.
__device__ __forceinline__ int swz64(int row, int kc) {
  return (row << 3) | (kc ^ (row & 7));
}
__device__ __forceinline__ void swz64_dec(int c, int& row, int& kc) {
  row = c >> 3;
  kc = (c & 7) ^ (row & 7);
}

// ---------------- weight transpose + cast ----------------
// bf16 variant (W2): W[K][N] -> Wt[N][K]
__global__ __launch_bounds__(256) void transpose_bf16_kernel(
    const float* __restrict__ W, bf16* __restrict__ Wt, int K, int N) {
  __shared__ float tile[32][33];
  int tx = threadIdx.x & 31;
  int ty = threadIdx.x >> 5;
  long col = (long)blockIdx.x * 32 + tx;
  long rowb = (long)blockIdx.y * 32;
#pragma unroll
  for (int i = 0; i < 32; i += 8)
    tile[ty + i][tx] = W[(rowb + ty + i) * N + col];
  __syncthreads();
  long ocol = rowb + tx;
  long orow = (long)blockIdx.x * 32 + ty;
#pragma unroll
  for (int i = 0; i < 32; i += 8)
    Wt[(orow + i) * K + ocol] = __float2bfloat16(tile[tx][ty + i]);
}

// fp8 variant (W1): W[K][N] -> Wt[N][K] fp8 e4m3 * W1_SCALE, k-permuted.
__global__ __launch_bounds__(256) void transpose_fp8_kernel(
    const float* __restrict__ W, u8* __restrict__ Wt, int K, int N) {
  __shared__ float tile[32][33];
  int tx = threadIdx.x & 31;
  int ty = threadIdx.x >> 5;
  long col = (long)blockIdx.x * 32 + tx;
  long rowb = (long)blockIdx.y * 32;
#pragma unroll
  for (int i = 0; i < 32; i += 8)
    tile[ty + i][tx] = W[(rowb + ty + i) * N + col];
  __syncthreads();
  long ocol = rowb + kperm(tx);  // rowb is a multiple of 32; permute within group
  long orow = (long)blockIdx.x * 32 + ty;
#pragma unroll
  for (int i = 0; i < 32; i += 8)
    Wt[(orow + i) * K + ocol] = to_fp8(tile[tx][ty + i] * W1_SCALE);
}

// ---------------- split RMSNorm -> fp8 (k-permuted, *XN_SCALE) ----------------
__global__ __launch_bounds__(256) void rmsnorm_kernel(
    const float* __restrict__ x, const float* __restrict__ ls,
    const float* __restrict__ rs, const float* __restrict__ ss,
    u8* __restrict__ xn8) {
  int token = blockIdx.x;
  int tid = threadIdx.x;  // 256 threads, 4 floats each
  const float4* xt = (const float4*)(x + (long)token * DIMS);
  float4 v = xt[tid];
  float s = v.x * v.x + v.y * v.y + v.z * v.z + v.w * v.w;
#pragma unroll
  for (int d = 32; d > 0; d >>= 1) s += __shfl_down(s, d);
  __shared__ float parts[4];
  if ((tid & 63) == 0) parts[tid >> 6] = s;
  __syncthreads();
  int j = tid * 4;
  bool left = j < 512;
  float sum = left ? (parts[0] + parts[1]) : (parts[2] + parts[3]);
  float n = sqrtf(sum * (1.0f / 512.0f));  // ||v||*d^-1/2
  float inv = 1.0f / (n + 1e-8f);
  const float4* sc = (const float4*)(left ? ls : rs);
  float4 g = sc[left ? tid : tid - 128];
  float4 p = ((const float4*)ss)[tid];
  u8 q[4];
  q[0] = to_fp8(v.x * g.x * inv * p.x * XN_SCALE);
  q[1] = to_fp8(v.y * g.y * inv * p.y * XN_SCALE);
  q[2] = to_fp8(v.z * g.z * inv * p.z * XN_SCALE);
  q[3] = to_fp8(v.w * g.w * inv * p.w * XN_SCALE);
  // kperm preserves bits 0-1 (j mult of 4) -> 4-byte aligned store
  *(uint32_t*)(xn8 + (long)token * DIMS + kperm(j)) = *(uint32_t*)q;
}

// ---------------- GEMM1 fp8: 256x128 block, BK=64, DOUBLE-BUFFERED ----------------
// 4 waves x (128x64) via mfma_f32_32x32x16_fp8_fp8 (bf16 rate, half the LDS bytes).
// Swapped operands: D col(lane&31)=token, D row=channel -> 8B packed bf16 stores.
// LDS rows = 64 fp8 = 64 B, swz32 bank swizzle; one b128 read feeds 2 MFMA k-slices.
__device__ __forceinline__ void g1f8_stage(const u8* __restrict__ A,
                                           const u8* __restrict__ Bt,
                                           long arow0, long brow0, int k0,
                                           int wave, int lane, u8* As, u8* Bs) {
  const int K = DIMS;
#pragma unroll
  for (int i = 0; i < 4; i++) {  // A: 1024 chunks (256 rows x 4)
    int c = (wave * 4 + i) * 64 + lane;
    int row, kc; swz32_dec(c, row, kc);
    async_copy16(A + (arow0 + row) * K + k0 + kc * 16, (char*)As + (wave * 4 + i) * 1024);
  }
#pragma unroll
  for (int i = 0; i < 2; i++) {  // B: 512 chunks (128 rows x 4)
    int c = (wave * 2 + i) * 64 + lane;
    int row, kc; swz32_dec(c, row, kc);
    async_copy16(Bt + (brow0 + row) * K + k0 + kc * 16, (char*)Bs + (wave * 2 + i) * 1024);
  }
}

__global__ __launch_bounds__(256, 2) void gemm1_fp8(
    const u8* __restrict__ A, const u8* __restrict__ Bt, bf16* __restrict__ C) {
  __shared__ __align__(16) u8 As0[256 * 64], As1[256 * 64];  // 16 KB each
  __shared__ __align__(16) u8 Bs0[128 * 64], Bs1[128 * 64];  // 8 KB each
  int tid = threadIdx.x;
  int lane = tid & 63, wave = tid >> 6;
  int wm = wave & 1, wn = wave >> 1;
  long arow0 = (long)blockIdx.y * 256;
  long brow0 = (long)blockIdx.x * 128;
  int m_lane = lane & 31, q4 = lane >> 5;
  f32x16 acc[4][2] = {};

  g1f8_stage(A, Bt, arow0, brow0, 0, wave, lane, As0, Bs0);
  __syncthreads();  // cold fill, once

  for (int it = 0; it < 16; it += 2) {
    // ---- body A: compute buf0, prefetch buf1 ----
    {
      v2i64 af[2][4], bfr[2][2];
#pragma unroll
      for (int p = 0; p < 2; p++) {  // pair of 16-k slices per read
#pragma unroll
        for (int mt = 0; mt < 4; mt++)
          af[p][mt] = *(const v2i64*)(As0 + swz32(wm * 128 + mt * 32 + m_lane, p * 2 + q4) * 16);
#pragma unroll
        for (int nt = 0; nt < 2; nt++)
          bfr[p][nt] = *(const v2i64*)(Bs0 + swz32(wn * 64 + nt * 32 + m_lane, p * 2 + q4) * 16);
      }
      g1f8_stage(A, Bt, arow0, brow0, (it + 1) * 64, wave, lane, As1, Bs1);
#pragma unroll
      for (int p = 0; p < 2; p++)
#pragma unroll
        for (int mt = 0; mt < 4; mt++)
#pragma unroll
          for (int nt = 0; nt < 2; nt++) {
            acc[mt][nt] = __builtin_amdgcn_mfma_f32_32x32x16_fp8_fp8(bfr[p][nt][0], af[p][mt][0], acc[mt][nt], 0, 0, 0);
            acc[mt][nt] = __builtin_amdgcn_mfma_f32_32x32x16_fp8_fp8(bfr[p][nt][1], af[p][mt][1], acc[mt][nt], 0, 0, 0);
          }
      __syncthreads();
    }
    // ---- body B: compute buf1, prefetch buf0 ----
    {
      v2i64 af[2][4], bfr[2][2];
#pragma unroll
      for (int p = 0; p < 2; p++) {
#pragma unroll
        for (int mt = 0; mt < 4; mt++)
          af[p][mt] = *(const v2i64*)(As1 + swz32(wm * 128 + mt * 32 + m_lane, p * 2 + q4) * 16);
#pragma unroll
        for (int nt = 0; nt < 2; nt++)
          bfr[p][nt] = *(const v2i64*)(Bs1 + swz32(wn * 64 + nt * 32 + m_lane, p * 2 + q4) * 16);
      }
      if (it + 2 < 16)
        g1f8_stage(A, Bt, arow0, brow0, (it + 2) * 64, wave, lane, As0, Bs0);
#pragma unroll
      for (int p = 0; p < 2; p++)
#pragma unroll
        for (int mt = 0; mt < 4; mt++)
#pragma unroll
          for (int nt = 0; nt < 2; nt++) {
            acc[mt][nt] = __builtin_amdgcn_mfma_f32_32x32x16_fp8_fp8(bfr[p][nt][0], af[p][mt][0], acc[mt][nt], 0, 0, 0);
            acc[mt][nt] = __builtin_amdgcn_mfma_f32_32x32x16_fp8_fp8(bfr[p][nt][1], af[p][mt][1], acc[mt][nt], 0, 0, 0);
          }
      __syncthreads();
    }
  }
  // token = arow0 + wm*128 + mt*32 + m_lane; channel = brow0 + wn*64 + nt*32 + g*8 + q4*4 + j
#pragma unroll
  for (int mt = 0; mt < 4; mt++) {
    long row = arow0 + wm * 128 + mt * 32 + m_lane;
#pragma unroll
    for (int nt = 0; nt < 2; nt++) {
#pragma unroll
      for (int g = 0; g < 4; g++) {
        long col = brow0 + wn * 64 + nt * 32 + g * 8 + q4 * 4;
        bf16 tmp[4];
#pragma unroll
        for (int j = 0; j < 4; j++)
          tmp[j] = __float2bfloat16(acc[mt][nt][g * 4 + j] * INV_SCALE);
        *(uint2*)(C + row * N1 + col) = *(uint2*)tmp;
      }
    }
  }
}

// ---------------- GEMM2: 128x128 block, BK=64, DOUBLE-BUFFERED, fused residual ----------------
__device__ __forceinline__ void g2_stage(const bf16* __restrict__ A,
                                         const bf16* __restrict__ Bt,
                                         long arow0, long brow0, int k0, int K,
                                         int wave, int lane, bf16* As, bf16* Bs) {
#pragma unroll
  for (int i = 0; i < 4; i++) {  // 1024 chunks each (128 rows x 64)
    int c = (wave * 4 + i) * 64 + lane;
    int row, kc; swz64_dec(c, row, kc);
    async_copy16(A + (arow0 + row) * K + k0 + kc * 8, (char*)As + (wave * 4 + i) * 1024);
    async_copy16(Bt + (brow0 + row) * K + k0 + kc * 8, (char*)Bs + (wave * 4 + i) * 1024);
  }
}

__global__ __launch_bounds__(256) void gemm2_resid(
    const bf16* __restrict__ A, const bf16* __restrict__ Bt,
    float* __restrict__ C, const float* __restrict__ resid) {
  __shared__ __align__(16) bf16 As0[128 * 64], As1[128 * 64];  // 16 KB each
  __shared__ __align__(16) bf16 Bs0[128 * 64], Bs1[128 * 64];
  const int K = STATE, N = DIMS;
  int tid = threadIdx.x;
  int lane = tid & 63, wave = tid >> 6;
  int wm = wave & 1, wn = wave >> 1;
  long arow0 = (long)blockIdx.y * 128;
  long brow0 = (long)blockIdx.x * 128;
  int r = lane & 15, q = lane >> 4;
  f32x4 acc[4][4] = {};

  g2_stage(A, Bt, arow0, brow0, 0, K, wave, lane, As0, Bs0);
  __syncthreads();

  for (int it = 0; it < 32; it += 2) {
    {
      const bf16x8* AsV = (const bf16x8*)As0;
      const bf16x8* BsV = (const bf16x8*)Bs0;
      bf16x8 af[2][4], bfr[2][4];
#pragma unroll
      for (int ks = 0; ks < 2; ks++) {
#pragma unroll
        for (int mt = 0; mt < 4; mt++) af[ks][mt] = AsV[swz64(wm * 64 + mt * 16 + r, ks * 4 + q)];
#pragma unroll
        for (int nt = 0; nt < 4; nt++) bfr[ks][nt] = BsV[swz64(wn * 64 + nt * 16 + r, ks * 4 + q)];
      }
      g2_stage(A, Bt, arow0, brow0, (it + 1) * 64, K, wave, lane, As1, Bs1);
#pragma unroll
      for (int ks = 0; ks < 2; ks++)
#pragma unroll
        for (int mt = 0; mt < 4; mt++)
#pragma unroll
          for (int nt = 0; nt < 4; nt++)
            acc[mt][nt] = __builtin_amdgcn_mfma_f32_16x16x32_bf16(bfr[ks][nt], af[ks][mt], acc[mt][nt], 0, 0, 0);
      __syncthreads();
    }
    {
      const bf16x8* AsV = (const bf16x8*)As1;
      const bf16x8* BsV = (const bf16x8*)Bs1;
      bf16x8 af[2][4], bfr[2][4];
#pragma unroll
      for (int ks = 0; ks < 2; ks++) {
#pragma unroll
        for (int mt = 0; mt < 4; mt++) af[ks][mt] = AsV[swz64(wm * 64 + mt * 16 + r, ks * 4 + q)];
#pragma unroll
        for (int nt = 0; nt < 4; nt++) bfr[ks][nt] = BsV[swz64(wn * 64 + nt * 16 + r, ks * 4 + q)];
      }
      if (it + 2 < 32)
        g2_stage(A, Bt, arow0, brow0, (it + 2) * 64, K, wave, lane, As0, Bs0);
#pragma unroll
      for (int ks = 0; ks < 2; ks++)
#pragma unroll
        for (int mt = 0; mt < 4; mt++)
#pragma unroll
          for (int nt = 0; nt < 4; nt++)
            acc[mt][nt] = __builtin_amdgcn_mfma_f32_16x16x32_bf16(bfr[ks][nt], af[ks][mt], acc[mt][nt], 0, 0, 0);
      __syncthreads();
    }
  }

  // token = lane&15 (mt tile), channel = q*4+reg (nt tile) -> float4 epilogue.
#pragma unroll
  for (int mt = 0; mt < 4; mt++) {
    long row = arow0 + wm * 64 + mt * 16 + r;
#pragma unroll
    for (int nt = 0; nt < 4; nt++) {
      long col = brow0 + wn * 64 + nt * 16 + q * 4;
      float4 rv = *(const float4*)(resid + row * N + col);
      float4 ov;
      ov.x = acc[mt][nt][0] + rv.x;
      ov.y = acc[mt][nt][1] + rv.y;
      ov.z = acc[mt][nt][2] + rv.z;
      ov.w = acc[mt][nt][3] + rv.w;
      *(float4*)(C + row * N + col) = ov;
    }
  }
}

// ---------------- chunked gated linear scan ----------------
// h_t = a_t*h_{t-1} + u_t, a_t = sigmoid(Kraw_{t-1}) (a_0=1),
// u_t = uraw_t*sigmoid(gin_t)*(1-sigmoid(Kraw_t)). Chunk composes to h_out = A*h_in + U.

__global__ __launch_bounds__(256) void chunk_summary_kernel(
    const bf16* __restrict__ C1, float* __restrict__ carryA,
    float* __restrict__ carryU) {
  int b = blockIdx.x;
  int ch = blockIdx.y * 256 + threadIdx.x;
  int chunk = blockIdx.z;
  int t0 = chunk * CHUNKL;
  long base = ((long)b * SEQ) * N1 + ch;
  float kp = 0.0f;
  if (chunk != 0) kp = __bfloat162float(C1[base + (long)(t0 - 1) * N1]);
  float a_first = (chunk == 0) ? 1.0f : sigmoidf_(kp);
  float A = 1.0f, U = 0.0f;
#pragma unroll 8
  for (int t = t0; t < t0 + CHUNKL; t++) {
    long off = base + (long)t * N1;
    float kraw = __bfloat162float(C1[off]);
    float uraw = __bfloat162float(C1[off + 2048]);
    float gin  = __bfloat162float(C1[off + 4096]);
    float a = (t == t0) ? a_first : sigmoidf_(kp);
    float sK = sigmoidf_(kraw);
    float u = uraw * sigmoidf_(gin) * (1.0f - sK);
    A *= a;
    U = a * U + u;
    kp = kraw;
  }
  int cidx = (b * NCHUNK + chunk) * STATE + ch;
  carryA[cidx] = A;
  carryU[cidx] = U;
}

__global__ __launch_bounds__(256) void carry_scan_kernel(
    const float* __restrict__ carryA, const float* __restrict__ carryU,
    float* __restrict__ carryIn) {
  int idx = blockIdx.x * 256 + threadIdx.x;  // b*STATE + ch
  int b = idx >> 11;
  int ch = idx & 2047;
  float h = 0.0f;
#pragma unroll
  for (int c = 0; c < NCHUNK; c++) {
    int cidx = (b * NCHUNK + c) * STATE + ch;
    carryIn[cidx] = h;
    h = carryA[cidx] * h + carryU[cidx];
  }
}

__global__ __launch_bounds__(256) void scan_chunk_kernel(
    const bf16* __restrict__ C1, const float* __restrict__ carryIn,
    bf16* __restrict__ out) {
  int b = blockIdx.x;
  int c0 = blockIdx.y * 32;
  int chunk = blockIdx.z;
  int tstart = chunk * CHUNKL;
  __shared__ float a_s[32][65], u_s[32][65], h_s[32][65];
  int tid = threadIdx.x;
  int lane = tid & 63, wave = tid >> 6;
  int cc = tid & 31;
  int tq = tid >> 5;

  float carryH[8], carryK[8];
#pragma unroll
  for (int i = 0; i < 8; i++) {
    int ch = c0 + wave * 8 + i;
    carryH[i] = carryIn[(b * NCHUNK + chunk) * STATE + ch];
    carryK[i] = (chunk == 0)
                    ? 1.0f
                    : sigmoidf_(__bfloat162float(
                          C1[((long)(b * SEQ + tstart - 1)) * N1 + ch]));
  }

  float g_r[8];
  for (int t0 = tstart; t0 < tstart + CHUNKL; t0 += 64) {
#pragma unroll
    for (int i = 0; i < 8; i++) {
      int t = tq * 8 + i;
      long rowoff = ((long)(b * SEQ + t0 + t)) * N1 + c0 + cc;
      float kraw = __bfloat162float(C1[rowoff]);
      float uraw = __bfloat162float(C1[rowoff + 2048]);
      float gin  = __bfloat162float(C1[rowoff + 4096]);
      float gout = __bfloat162float(C1[rowoff + 6144]);
      float aK = sigmoidf_(kraw);
      a_s[cc][t] = aK;
      u_s[cc][t] = uraw * sigmoidf_(gin) * (1.0f - aK);
      g_r[i] = sigmoidf_(gout);
    }
    __syncthreads();
#pragma unroll
    for (int i = 0; i < 8; i++) {
      int ch = wave * 8 + i;
      float aK = a_s[ch][lane];
      float u = u_s[ch][lane];
      float a = __shfl_up(aK, 1);
      if (lane == 0) a = carryK[i];
      float A = a, U = u;
#pragma unroll
      for (int d = 1; d < 64; d <<= 1) {
        float Au = __shfl_up(A, d);
        float Uu = __shfl_up(U, d);
        if (lane >= d) { U += A * Uu; A *= Au; }
      }
      float h = U + A * carryH[i];
      carryH[i] = __shfl(h, 63);
      carryK[i] = __shfl(aK, 63);
      h_s[ch][lane] = h;
    }
    __syncthreads();
#pragma unroll
    for (int i = 0; i < 8; i++) {
      int t = tq * 8 + i;
      out[((long)(b * SEQ + t0 + t)) * STATE + c0 + cc] =
          __float2bfloat16(h_s[cc][t] * g_r[i]);
    }
    __syncthreads();
  }
}

extern "C" void kernel_launch(void* const* d_in, const int* in_sizes, int n_in,
                              void* d_out, int out_size, void* d_ws, size_t ws_size,
                              hipStream_t stream) {
  const float* x    = (const float*)d_in[0];
  const float* ls   = (const float*)d_in[1];
  const float* rs   = (const float*)d_in[2];
  const float* ss   = (const float*)d_in[3];
  const float* Wk   = (const float*)d_in[4];
  const float* Wugg = (const float*)d_in[5];
  const float* Wout = (const float*)d_in[6];
  float* out = (float*)d_out;

  // workspace layout (~188 MB)
  char* ws = (char*)d_ws;
  u8*   W1f8 = (u8*)ws;                                    // [8192][1024] fp8 = 8 MB
  bf16* W2t  = (bf16*)(ws + 8388608);                      // [1024][2048] bf16 = 4 MB
  u8*   xn8  = (u8*)(ws + 8388608 + 4194304);              // [8192][1024] fp8 = 8 MB
  bf16* C1   = (bf16*)(ws + 8388608 + 4194304 + 8388608);  // [8192][8192] bf16 = 134 MB
  bf16* sco  = (bf16*)(ws + 8388608 + 4194304 + 8388608 + 134217728); // [8192][2048]
  // carry buffers (3 x 512 KB) overlay xn8: xn8 is dead after gemm1.
  float* carryA  = (float*)xn8;
  float* carryU  = carryA + BATCH * NCHUNK * STATE;
  float* carryIn = carryU + BATCH * NCHUNK * STATE;

  // weights: W1 -> fp8 (scaled, k-permuted), W2 -> bf16, both transposed to [N][K]
  transpose_fp8_kernel<<<dim3(STATE / 32, DIMS / 32), 256, 0, stream>>>(Wk, W1f8, DIMS, STATE);
  transpose_fp8_kernel<<<dim3(3 * STATE / 32, DIMS / 32), 256, 0, stream>>>(
      Wugg, W1f8 + (long)STATE * DIMS, DIMS, 3 * STATE);
  transpose_bf16_kernel<<<dim3(DIMS / 32, STATE / 32), 256, 0, stream>>>(Wout, W2t, STATE, DIMS);

  rmsnorm_kernel<<<TOKENS, 256, 0, stream>>>(x, ls, rs, ss, xn8);

  gemm1_fp8<<<dim3(N1 / 128, TOKENS / 256), 256, 0, stream>>>(xn8, W1f8, C1);

  chunk_summary_kernel<<<dim3(BATCH, STATE / 256, NCHUNK), 256, 0, stream>>>(
      C1, carryA, carryU);
  carry_scan_kernel<<<dim3(BATCH * STATE / 256), 256, 0, stream>>>(
      carryA, carryU, carryIn);
  scan_chunk_kernel<<<dim3(BATCH, STATE / 32, NCHUNK), 256, 0, stream>>>(
      C1, carryIn, sco);

  gemm2_resid<<<dim3(DIMS / 128, TOKENS / 128), 256, 0, stream>>>(
      sco, W2t, out, x);
}

// Round 9
// 387.349 us; speedup vs baseline: 1.2344x; 1.0451x over previous
//
#include <hip/hip_runtime.h>
#include <hip/hip_bf16.h>
#include <hip/hip_fp8.h>
#include <stdint.h>

#define DIMS 1024
#define STATE 2048
#define BATCH 4
#define SEQ 2048
#define TOKENS 8192   // BATCH*SEQ
#define N1 8192       // fused GEMM1 output columns, INTERLEAVED: col = ch*4 + stream
#define NCHUNK 16
#define CHUNKL (SEQ / NCHUNK)   // 128

typedef __hip_bfloat16 bf16;
typedef unsigned char u8;
typedef unsigned short u16;
typedef __attribute__((ext_vector_type(8))) short bf16x8;
typedef __attribute__((ext_vector_type(4))) float f32x4;
typedef __attribute__((ext_vector_type(16))) float f32x16;
typedef __attribute__((ext_vector_type(2))) long v2i64;

// static fp8 scales: xn*32, W1*256 -> acc/8192 in epilogue
#define XN_SCALE 32.0f
#define W1_SCALE 256.0f
#define INV_SCALE (1.0f / 8192.0f)

__device__ __forceinline__ float sigmoidf_(float x) {
  return 1.0f / (1.0f + __expf(-x));
}

__device__ __forceinline__ u8 to_fp8(float f) {
  __hip_fp8_e4m3 h(f);
  return h.__x;
}

// exact bf16(bits)->f32
__device__ __forceinline__ float b2f(u16 v) {
  union { uint32_t u; float f; } w;
  w.u = ((uint32_t)v) << 16;
  return w.f;
}

// k-permutation baked into fp8 producers: swap bits 3<->4 of the k index so a
// lane's MFMA operands for two consecutive 16-k slices are 16 CONTIGUOUS bytes.
__device__ __forceinline__ int kperm(int k) {
  return (k & ~24) | ((k & 8) << 1) | ((k & 16) >> 1);
}

// async global->LDS, 16B per lane. LDS dest must be wave-uniform base; HW does base + lane*16.
__device__ __forceinline__ void async_copy16(const void* g, void* l) {
  __builtin_amdgcn_global_load_lds(
      (const __attribute__((address_space(1))) void*)(uintptr_t)g,
      (__attribute__((address_space(3))) void*)(uint32_t)(uintptr_t)l,
      16, 0, 0);
}

// ---- LDS XOR swizzles ----
// 64 B rows (4 x 16B chunks): bank period = row pair.
__device__ __forceinline__ int swz32(int row, int kc) {
  int line = row >> 1;
  int sub = ((row & 1) << 2) | kc;
  return (line << 3) | (sub ^ (line & 7));
}
__device__ __forceinline__ void swz32_dec(int c, int& row, int& kc) {
  int line = c >> 3;
  int sub = (c & 7) ^ (line & 7);
  row = (line << 1) | (sub >> 2);
  kc = sub & 3;
}
// 128 B rows (8 x 16B chunks): one row == one bank period.
__device__ __forceinline__ int swz64(int row, int kc) {
  return (row << 3) | (kc ^ (row & 7));
}
__device__ __forceinline__ void swz64_dec(int c, int& row, int& kc) {
  row = c >> 3;
  kc = (c & 7) ^ (row & 7);
}

// ---------------- weight transpose + cast ----------------
// bf16 variant (W2): W[K][N] -> Wt[N][K]
__global__ __launch_bounds__(256) void transpose_bf16_kernel(
    const float* __restrict__ W, bf16* __restrict__ Wt, int K, int N) {
  __shared__ float tile[32][33];
  int tx = threadIdx.x & 31;
  int ty = threadIdx.x >> 5;
  long col = (long)blockIdx.x * 32 + tx;
  long rowb = (long)blockIdx.y * 32;
#pragma unroll
  for (int i = 0; i < 32; i += 8)
    tile[ty + i][tx] = W[(rowb + ty + i) * N + col];
  __syncthreads();
  long ocol = rowb + tx;
  long orow = (long)blockIdx.x * 32 + ty;
#pragma unroll
  for (int i = 0; i < 32; i += 8)
    Wt[(orow + i) * K + ocol] = __float2bfloat16(tile[tx][ty + i]);
}

// fp8 variant (W1): W[K][N] -> Wt[perm(N)][K] fp8 e4m3 * W1_SCALE, k-permuted.
// Output-channel interleave: fused col n (= local col + stream_base*2048 region)
// maps to dst row = ch*4 + stream, so C1 stores all 4 streams of a channel in
// 8 contiguous bytes -> vector loads in the scan passes.
__global__ __launch_bounds__(256) void transpose_fp8_kernel(
    const float* __restrict__ W, u8* __restrict__ Wt, int K, int N, int stream_base) {
  __shared__ float tile[32][33];
  int tx = threadIdx.x & 31;
  int ty = threadIdx.x >> 5;
  long col = (long)blockIdx.x * 32 + tx;
  long rowb = (long)blockIdx.y * 32;
#pragma unroll
  for (int i = 0; i < 32; i += 8)
    tile[ty + i][tx] = W[(rowb + ty + i) * N + col];
  __syncthreads();
  long ocol = rowb + kperm(tx);  // rowb multiple of 32; permute within group
  long orow = (long)blockIdx.x * 32 + ty;  // original fused channel index
#pragma unroll
  for (int i = 0; i < 32; i += 8) {
    long n = orow + i;
    long dstrow = ((n & 2047) << 2) | (stream_base + (n >> 11));
    Wt[dstrow * K + ocol] = to_fp8(tile[tx][ty + i] * W1_SCALE);
  }
}

// ---------------- split RMSNorm -> fp8 (k-permuted, *XN_SCALE) ----------------
__global__ __launch_bounds__(256) void rmsnorm_kernel(
    const float* __restrict__ x, const float* __restrict__ ls,
    const float* __restrict__ rs, const float* __restrict__ ss,
    u8* __restrict__ xn8) {
  int token = blockIdx.x;
  int tid = threadIdx.x;  // 256 threads, 4 floats each
  const float4* xt = (const float4*)(x + (long)token * DIMS);
  float4 v = xt[tid];
  float s = v.x * v.x + v.y * v.y + v.z * v.z + v.w * v.w;
#pragma unroll
  for (int d = 32; d > 0; d >>= 1) s += __shfl_down(s, d);
  __shared__ float parts[4];
  if ((tid & 63) == 0) parts[tid >> 6] = s;
  __syncthreads();
  int j = tid * 4;
  bool left = j < 512;
  float sum = left ? (parts[0] + parts[1]) : (parts[2] + parts[3]);
  float n = sqrtf(sum * (1.0f / 512.0f));  // ||v||*d^-1/2
  float inv = 1.0f / (n + 1e-8f);
  const float4* sc = (const float4*)(left ? ls : rs);
  float4 g = sc[left ? tid : tid - 128];
  float4 p = ((const float4*)ss)[tid];
  u8 q[4];
  q[0] = to_fp8(v.x * g.x * inv * p.x * XN_SCALE);
  q[1] = to_fp8(v.y * g.y * inv * p.y * XN_SCALE);
  q[2] = to_fp8(v.z * g.z * inv * p.z * XN_SCALE);
  q[3] = to_fp8(v.w * g.w * inv * p.w * XN_SCALE);
  *(uint32_t*)(xn8 + (long)token * DIMS + kperm(j)) = *(uint32_t*)q;
}

// ---------------- GEMM1 fp8: 256x128 block, BK=64, DOUBLE-BUFFERED ----------------
// 4 waves x (128x64) via mfma_f32_32x32x16_fp8_fp8. Swapped operands:
// D col(lane&31)=token, D row=channel-group col -> 8B packed bf16 stores.
__device__ __forceinline__ void g1f8_stage(const u8* __restrict__ A,
                                           const u8* __restrict__ Bt,
                                           long arow0, long brow0, int k0,
                                           int wave, int lane, u8* As, u8* Bs) {
  const int K = DIMS;
#pragma unroll
  for (int i = 0; i < 4; i++) {  // A: 1024 chunks (256 rows x 4)
    int c = (wave * 4 + i) * 64 + lane;
    int row, kc; swz32_dec(c, row, kc);
    async_copy16(A + (arow0 + row) * K + k0 + kc * 16, (char*)As + (wave * 4 + i) * 1024);
  }
#pragma unroll
  for (int i = 0; i < 2; i++) {  // B: 512 chunks (128 rows x 4)
    int c = (wave * 2 + i) * 64 + lane;
    int row, kc; swz32_dec(c, row, kc);
    async_copy16(Bt + (brow0 + row) * K + k0 + kc * 16, (char*)Bs + (wave * 2 + i) * 1024);
  }
}

__global__ __launch_bounds__(256, 2) void gemm1_fp8(
    const u8* __restrict__ A, const u8* __restrict__ Bt, bf16* __restrict__ C) {
  __shared__ __align__(16) u8 As0[256 * 64], As1[256 * 64];  // 16 KB each
  __shared__ __align__(16) u8 Bs0[128 * 64], Bs1[128 * 64];  // 8 KB each
  int tid = threadIdx.x;
  int lane = tid & 63, wave = tid >> 6;
  int wm = wave & 1, wn = wave >> 1;
  long arow0 = (long)blockIdx.y * 256;
  long brow0 = (long)blockIdx.x * 128;
  int m_lane = lane & 31, q4 = lane >> 5;
  f32x16 acc[4][2] = {};

  g1f8_stage(A, Bt, arow0, brow0, 0, wave, lane, As0, Bs0);
  __syncthreads();  // cold fill, once

  for (int it = 0; it < 16; it += 2) {
    // ---- body A: compute buf0, prefetch buf1 ----
    {
      v2i64 af[2][4], bfr[2][2];
#pragma unroll
      for (int p = 0; p < 2; p++) {
#pragma unroll
        for (int mt = 0; mt < 4; mt++)
          af[p][mt] = *(const v2i64*)(As0 + swz32(wm * 128 + mt * 32 + m_lane, p * 2 + q4) * 16);
#pragma unroll
        for (int nt = 0; nt < 2; nt++)
          bfr[p][nt] = *(const v2i64*)(Bs0 + swz32(wn * 64 + nt * 32 + m_lane, p * 2 + q4) * 16);
      }
      g1f8_stage(A, Bt, arow0, brow0, (it + 1) * 64, wave, lane, As1, Bs1);
#pragma unroll
      for (int p = 0; p < 2; p++)
#pragma unroll
        for (int mt = 0; mt < 4; mt++)
#pragma unroll
          for (int nt = 0; nt < 2; nt++) {
            acc[mt][nt] = __builtin_amdgcn_mfma_f32_32x32x16_fp8_fp8(bfr[p][nt][0], af[p][mt][0], acc[mt][nt], 0, 0, 0);
            acc[mt][nt] = __builtin_amdgcn_mfma_f32_32x32x16_fp8_fp8(bfr[p][nt][1], af[p][mt][1], acc[mt][nt], 0, 0, 0);
          }
      __syncthreads();
    }
    // ---- body B: compute buf1, prefetch buf0 ----
    {
      v2i64 af[2][4], bfr[2][2];
#pragma unroll
      for (int p = 0; p < 2; p++) {
#pragma unroll
        for (int mt = 0; mt < 4; mt++)
          af[p][mt] = *(const v2i64*)(As1 + swz32(wm * 128 + mt * 32 + m_lane, p * 2 + q4) * 16);
#pragma unroll
        for (int nt = 0; nt < 2; nt++)
          bfr[p][nt] = *(const v2i64*)(Bs1 + swz32(wn * 64 + nt * 32 + m_lane, p * 2 + q4) * 16);
      }
      if (it + 2 < 16)
        g1f8_stage(A, Bt, arow0, brow0, (it + 2) * 64, wave, lane, As0, Bs0);
#pragma unroll
      for (int p = 0; p < 2; p++)
#pragma unroll
        for (int mt = 0; mt < 4; mt++)
#pragma unroll
          for (int nt = 0; nt < 2; nt++) {
            acc[mt][nt] = __builtin_amdgcn_mfma_f32_32x32x16_fp8_fp8(bfr[p][nt][0], af[p][mt][0], acc[mt][nt], 0, 0, 0);
            acc[mt][nt] = __builtin_amdgcn_mfma_f32_32x32x16_fp8_fp8(bfr[p][nt][1], af[p][mt][1], acc[mt][nt], 0, 0, 0);
          }
      __syncthreads();
    }
  }
#pragma unroll
  for (int mt = 0; mt < 4; mt++) {
    long row = arow0 + wm * 128 + mt * 32 + m_lane;  // token
#pragma unroll
    for (int nt = 0; nt < 2; nt++) {
#pragma unroll
      for (int g = 0; g < 4; g++) {
        long col = brow0 + wn * 64 + nt * 32 + g * 8 + q4 * 4;  // interleaved channel col
        bf16 tmp[4];
#pragma unroll
        for (int j = 0; j < 4; j++)
          tmp[j] = __float2bfloat16(acc[mt][nt][g * 4 + j] * INV_SCALE);
        *(uint2*)(C + row * N1 + col) = *(uint2*)tmp;
      }
    }
  }
}

// ---------------- GEMM2: 128x128 block, BK=64, DOUBLE-BUFFERED, fused residual ----------------
__device__ __forceinline__ void g2_stage(const bf16* __restrict__ A,
                                         const bf16* __restrict__ Bt,
                                         long arow0, long brow0, int k0, int K,
                                         int wave, int lane, bf16* As, bf16* Bs) {
#pragma unroll
  for (int i = 0; i < 4; i++) {  // 1024 chunks each (128 rows x 64)
    int c = (wave * 4 + i) * 64 + lane;
    int row, kc; swz64_dec(c, row, kc);
    async_copy16(A + (arow0 + row) * K + k0 + kc * 8, (char*)As + (wave * 4 + i) * 1024);
    async_copy16(Bt + (brow0 + row) * K + k0 + kc * 8, (char*)Bs + (wave * 4 + i) * 1024);
  }
}

__global__ __launch_bounds__(256) void gemm2_resid(
    const bf16* __restrict__ A, const bf16* __restrict__ Bt,
    float* __restrict__ C, const float* __restrict__ resid) {
  __shared__ __align__(16) bf16 As0[128 * 64], As1[128 * 64];  // 16 KB each
  __shared__ __align__(16) bf16 Bs0[128 * 64], Bs1[128 * 64];
  const int K = STATE, N = DIMS;
  int tid = threadIdx.x;
  int lane = tid & 63, wave = tid >> 6;
  int wm = wave & 1, wn = wave >> 1;
  long arow0 = (long)blockIdx.y * 128;
  long brow0 = (long)blockIdx.x * 128;
  int r = lane & 15, q = lane >> 4;
  f32x4 acc[4][4] = {};

  g2_stage(A, Bt, arow0, brow0, 0, K, wave, lane, As0, Bs0);
  __syncthreads();

  for (int it = 0; it < 32; it += 2) {
    {
      const bf16x8* AsV = (const bf16x8*)As0;
      const bf16x8* BsV = (const bf16x8*)Bs0;
      bf16x8 af[2][4], bfr[2][4];
#pragma unroll
      for (int ks = 0; ks < 2; ks++) {
#pragma unroll
        for (int mt = 0; mt < 4; mt++) af[ks][mt] = AsV[swz64(wm * 64 + mt * 16 + r, ks * 4 + q)];
#pragma unroll
        for (int nt = 0; nt < 4; nt++) bfr[ks][nt] = BsV[swz64(wn * 64 + nt * 16 + r, ks * 4 + q)];
      }
      g2_stage(A, Bt, arow0, brow0, (it + 1) * 64, K, wave, lane, As1, Bs1);
#pragma unroll
      for (int ks = 0; ks < 2; ks++)
#pragma unroll
        for (int mt = 0; mt < 4; mt++)
#pragma unroll
          for (int nt = 0; nt < 4; nt++)
            acc[mt][nt] = __builtin_amdgcn_mfma_f32_16x16x32_bf16(bfr[ks][nt], af[ks][mt], acc[mt][nt], 0, 0, 0);
      __syncthreads();
    }
    {
      const bf16x8* AsV = (const bf16x8*)As1;
      const bf16x8* BsV = (const bf16x8*)Bs1;
      bf16x8 af[2][4], bfr[2][4];
#pragma unroll
      for (int ks = 0; ks < 2; ks++) {
#pragma unroll
        for (int mt = 0; mt < 4; mt++) af[ks][mt] = AsV[swz64(wm * 64 + mt * 16 + r, ks * 4 + q)];
#pragma unroll
        for (int nt = 0; nt < 4; nt++) bfr[ks][nt] = BsV[swz64(wn * 64 + nt * 16 + r, ks * 4 + q)];
      }
      if (it + 2 < 32)
        g2_stage(A, Bt, arow0, brow0, (it + 2) * 64, K, wave, lane, As0, Bs0);
#pragma unroll
      for (int ks = 0; ks < 2; ks++)
#pragma unroll
        for (int mt = 0; mt < 4; mt++)
#pragma unroll
          for (int nt = 0; nt < 4; nt++)
            acc[mt][nt] = __builtin_amdgcn_mfma_f32_16x16x32_bf16(bfr[ks][nt], af[ks][mt], acc[mt][nt], 0, 0, 0);
      __syncthreads();
    }
  }

#pragma unroll
  for (int mt = 0; mt < 4; mt++) {
    long row = arow0 + wm * 64 + mt * 16 + r;
#pragma unroll
    for (int nt = 0; nt < 4; nt++) {
      long col = brow0 + wn * 64 + nt * 16 + q * 4;
      float4 rv = *(const float4*)(resid + row * N + col);
      float4 ov;
      ov.x = acc[mt][nt][0] + rv.x;
      ov.y = acc[mt][nt][1] + rv.y;
      ov.z = acc[mt][nt][2] + rv.z;
      ov.w = acc[mt][nt][3] + rv.w;
      *(float4*)(C + row * N + col) = ov;
    }
  }
}

// ---------------- chunked gated linear scan (INTERLEAVED C1) ----------------
// C1 row layout: [ch*4+0]=Kraw, +1=uraw, +2=gin, +3=gout -> one uint2 per (ch,t).
// h_t = a_t*h_{t-1} + u_t, a_t = sigmoid(Kraw_{t-1}) (a_0=1),
// u_t = uraw_t*sigmoid(gin_t)*(1-sigmoid(Kraw_t)). Chunk composes to h_out = A*h_in + U.

__global__ __launch_bounds__(256) void chunk_summary_kernel(
    const bf16* __restrict__ C1, float* __restrict__ carryA,
    float* __restrict__ carryU) {
  int b = blockIdx.x;
  int ch = blockIdx.y * 256 + threadIdx.x;
  int chunk = blockIdx.z;
  int t0 = chunk * CHUNKL;
  const bf16* base = C1 + ((long)b * SEQ) * N1 + ch * 4;
  float kp = 0.0f;
  if (chunk != 0) kp = __bfloat162float(base[(long)(t0 - 1) * N1]);
  float a_first = (chunk == 0) ? 1.0f : sigmoidf_(kp);
  float A = 1.0f, U = 0.0f;
#pragma unroll 8
  for (int t = t0; t < t0 + CHUNKL; t++) {
    union { uint2 u2; u16 h[4]; } w;
    w.u2 = *(const uint2*)(base + (long)t * N1);
    float kraw = b2f(w.h[0]);
    float uraw = b2f(w.h[1]);
    float gin  = b2f(w.h[2]);
    float a = (t == t0) ? a_first : sigmoidf_(kp);
    float sK = sigmoidf_(kraw);
    float u = uraw * sigmoidf_(gin) * (1.0f - sK);
    A *= a;
    U = a * U + u;
    kp = kraw;
  }
  int cidx = (b * NCHUNK + chunk) * STATE + ch;
  carryA[cidx] = A;
  carryU[cidx] = U;
}

__global__ __launch_bounds__(256) void carry_scan_kernel(
    const float* __restrict__ carryA, const float* __restrict__ carryU,
    float* __restrict__ carryIn) {
  int idx = blockIdx.x * 256 + threadIdx.x;  // b*STATE + ch
  int b = idx >> 11;
  int ch = idx & 2047;
  float h = 0.0f;
#pragma unroll
  for (int c = 0; c < NCHUNK; c++) {
    int cidx = (b * NCHUNK + c) * STATE + ch;
    carryIn[cidx] = h;
    h = carryA[cidx] * h + carryU[cidx];
  }
}

__global__ __launch_bounds__(256) void scan_chunk_kernel(
    const bf16* __restrict__ C1, const float* __restrict__ carryIn,
    bf16* __restrict__ out) {
  int b = blockIdx.x;
  int c0 = blockIdx.y * 32;
  int chunk = blockIdx.z;
  int tstart = chunk * CHUNKL;
  __shared__ float a_s[32][65], u_s[32][65], h_s[32][65];
  int tid = threadIdx.x;
  int lane = tid & 63, wave = tid >> 6;
  int cc = tid & 31;
  int tq = tid >> 5;

  float carryH[8], carryK[8];
#pragma unroll
  for (int i = 0; i < 8; i++) {
    int ch = c0 + wave * 8 + i;
    carryH[i] = carryIn[(b * NCHUNK + chunk) * STATE + ch];
    carryK[i] = (chunk == 0)
                    ? 1.0f
                    : sigmoidf_(__bfloat162float(
                          C1[((long)(b * SEQ + tstart - 1)) * N1 + ch * 4]));
  }

  float g_r[8];
  for (int t0 = tstart; t0 < tstart + CHUNKL; t0 += 64) {
    // load + gate: one uint2 per (ch,t); lanes contiguous across channels
#pragma unroll
    for (int i = 0; i < 8; i++) {
      int t = tq * 8 + i;
      union { uint2 u2; u16 h[4]; } w;
      w.u2 = *(const uint2*)(C1 + ((long)(b * SEQ + t0 + t)) * N1 + (c0 + cc) * 4);
      float kraw = b2f(w.h[0]);
      float uraw = b2f(w.h[1]);
      float gin  = b2f(w.h[2]);
      float gout = b2f(w.h[3]);
      float aK = sigmoidf_(kraw);
      a_s[cc][t] = aK;
      u_s[cc][t] = uraw * sigmoidf_(gin) * (1.0f - aK);
      g_r[i] = sigmoidf_(gout);
    }
    __syncthreads();
#pragma unroll
    for (int i = 0; i < 8; i++) {
      int ch = wave * 8 + i;
      float aK = a_s[ch][lane];
      float u = u_s[ch][lane];
      float a = __shfl_up(aK, 1);
      if (lane == 0) a = carryK[i];
      float A = a, U = u;
#pragma unroll
      for (int d = 1; d < 64; d <<= 1) {
        float Au = __shfl_up(A, d);
        float Uu = __shfl_up(U, d);
        if (lane >= d) { U += A * Uu; A *= Au; }
      }
      float h = U + A * carryH[i];
      carryH[i] = __shfl(h, 63);
      carryK[i] = __shfl(aK, 63);
      h_s[ch][lane] = h;
    }
    __syncthreads();
#pragma unroll
    for (int i = 0; i < 8; i++) {
      int t = tq * 8 + i;
      out[((long)(b * SEQ + t0 + t)) * STATE + c0 + cc] =
          __float2bfloat16(h_s[cc][t] * g_r[i]);
    }
    __syncthreads();
  }
}

extern "C" void kernel_launch(void* const* d_in, const int* in_sizes, int n_in,
                              void* d_out, int out_size, void* d_ws, size_t ws_size,
                              hipStream_t stream) {
  const float* x    = (const float*)d_in[0];
  const float* ls   = (const float*)d_in[1];
  const float* rs   = (const float*)d_in[2];
  const float* ss   = (const float*)d_in[3];
  const float* Wk   = (const float*)d_in[4];
  const float* Wugg = (const float*)d_in[5];
  const float* Wout = (const float*)d_in[6];
  float* out = (float*)d_out;

  // workspace layout (~188 MB)
  char* ws = (char*)d_ws;
  u8*   W1f8 = (u8*)ws;                                    // [8192][1024] fp8 = 8 MB (interleaved rows)
  bf16* W2t  = (bf16*)(ws + 8388608);                      // [1024][2048] bf16 = 4 MB
  u8*   xn8  = (u8*)(ws + 8388608 + 4194304);              // [8192][1024] fp8 = 8 MB
  bf16* C1   = (bf16*)(ws + 8388608 + 4194304 + 8388608);  // [8192][8192] bf16 = 134 MB
  bf16* sco  = (bf16*)(ws + 8388608 + 4194304 + 8388608 + 134217728); // [8192][2048]
  // carry buffers (3 x 512 KB) overlay xn8: xn8 is dead after gemm1.
  float* carryA  = (float*)xn8;
  float* carryU  = carryA + BATCH * NCHUNK * STATE;
  float* carryIn = carryU + BATCH * NCHUNK * STATE;

  // W1 -> fp8 (scaled, k-permuted, channel-interleaved rows), W2 -> bf16
  transpose_fp8_kernel<<<dim3(STATE / 32, DIMS / 32), 256, 0, stream>>>(
      Wk, W1f8, DIMS, STATE, 0);
  transpose_fp8_kernel<<<dim3(3 * STATE / 32, DIMS / 32), 256, 0, stream>>>(
      Wugg, W1f8, DIMS, 3 * STATE, 1);
  transpose_bf16_kernel<<<dim3(DIMS / 32, STATE / 32), 256, 0, stream>>>(Wout, W2t, STATE, DIMS);

  rmsnorm_kernel<<<TOKENS, 256, 0, stream>>>(x, ls, rs, ss, xn8);

  gemm1_fp8<<<dim3(N1 / 128, TOKENS / 256), 256, 0, stream>>>(xn8, W1f8, C1);

  chunk_summary_kernel<<<dim3(BATCH, STATE / 256, NCHUNK), 256, 0, stream>>>(
      C1, carryA, carryU);
  carry_scan_kernel<<<dim3(BATCH * STATE / 256), 256, 0, stream>>>(
      carryA, carryU, carryIn);
  scan_chunk_kernel<<<dim3(BATCH, STATE / 32, NCHUNK), 256, 0, stream>>>(
      C1, carryIn, sco);

  gemm2_resid<<<dim3(DIMS / 128, TOKENS / 128), 256, 0, stream>>>(
      sco, W2t, out, x);
}